// Round 1
// baseline (1834.840 us; speedup 1.0000x reference)
//
#include <hip/hip_runtime.h>

#define DEVINL __device__ __forceinline__

// ---------------------------------------------------------------- FPS
// One block per batch. Points + running min-dist live in registers
// (N/256 per thread). LDS copy of coords only for centroid broadcast.
// Matches jnp semantics: store current farthest, update dist with
// centroid, argmax (first occurrence on ties) -> next farthest.
template<int N, int NP>
__global__ __launch_bounds__(256) void fps_kernel(const float* __restrict__ xyz,
                                                  float* __restrict__ nxyz) {
  constexpr int PTS = N / 256;
  const int b = blockIdx.x, t = threadIdx.x;
  __shared__ float xs[N], ys[N], zs[N];
  __shared__ float swv[4];
  __shared__ int swi[4];
  __shared__ int sfar;
  float px[PTS], py[PTS], pz[PTS], dst[PTS];
  const float* base = xyz + (size_t)b * N * 3;
#pragma unroll
  for (int j = 0; j < PTS; ++j) {
    int i = t + j * 256;
    float x = base[i * 3 + 0], y = base[i * 3 + 1], z = base[i * 3 + 2];
    px[j] = x; py[j] = y; pz[j] = z;
    xs[i] = x; ys[i] = y; zs[i] = z;
    dst[j] = 1e10f;
  }
  __syncthreads();
  int far = 0;
  const int wv = t >> 6, ln = t & 63;
  for (int s = 0; s < NP; ++s) {
    float cx = xs[far], cy = ys[far], cz = zs[far];
    if (t == 0) {
      float* o = nxyz + ((size_t)b * NP + s) * 3;
      o[0] = cx; o[1] = cy; o[2] = cz;
    }
    float bv = -1.f; int bi = 0;
#pragma unroll
    for (int j = 0; j < PTS; ++j) {
      // no-fma, left-to-right: matches numpy elementwise + sum order
      float dx = __fsub_rn(px[j], cx), dy = __fsub_rn(py[j], cy), dz = __fsub_rn(pz[j], cz);
      float d = __fadd_rn(__fadd_rn(__fmul_rn(dx, dx), __fmul_rn(dy, dy)), __fmul_rn(dz, dz));
      float nd = fminf(dst[j], d);
      dst[j] = nd;
      int i = t + j * 256;
      if (nd > bv) { bv = nd; bi = i; }  // ascending i per thread -> first max kept
    }
#pragma unroll
    for (int m = 32; m >= 1; m >>= 1) {
      float ov = __shfl_xor(bv, m, 64);
      int   oi = __shfl_xor(bi, m, 64);
      if (ov > bv || (ov == bv && oi < bi)) { bv = ov; bi = oi; }
    }
    if (ln == 0) { swv[wv] = bv; swi[wv] = bi; }
    __syncthreads();
    if (t == 0) {
      float v = swv[0]; int ii = swi[0];
#pragma unroll
      for (int q = 1; q < 4; ++q)
        if (swv[q] > v || (swv[q] == v && swi[q] < ii)) { v = swv[q]; ii = swi[q]; }
      sfar = ii;
    }
    __syncthreads();
    far = sfar;
  }
}

// ---------------------------------------------------------------- ball query
// One wave per group. Chunked ballot compaction keeps the first NS
// in-radius indices in ascending order; pad with first hit.
template<int N, int NS>
__global__ __launch_bounds__(256) void bq_kernel(const float* __restrict__ pts,
                                                 const float* __restrict__ centers,
                                                 int* __restrict__ gidx, int Q, float r2) {
  const int wv = threadIdx.x >> 6, ln = threadIdx.x & 63;
  const int g = blockIdx.x * 4 + wv;
  const int b = g / Q, q = g % Q;
  const float* pb = pts + (size_t)b * N * 3;
  const float* c = centers + ((size_t)b * Q + q) * 3;
  const float cx = c[0], cy = c[1], cz = c[2];
  __shared__ int gbuf[4][NS];
  int taken = 0;
  for (int base = 0; base < N; base += 64) {
    if (taken >= NS) break;  // uniform across wave
    int i = base + ln;
    float dx = __fsub_rn(pb[i * 3 + 0], cx), dy = __fsub_rn(pb[i * 3 + 1], cy),
          dz = __fsub_rn(pb[i * 3 + 2], cz);
    float d = __fadd_rn(__fadd_rn(__fmul_rn(dx, dx), __fmul_rn(dy, dy)), __fmul_rn(dz, dz));
    bool in = (d <= r2);
    unsigned long long mk = __ballot(in);
    int rank = __popcll(mk & ((1ull << ln) - 1ull));
    int pos = taken + rank;
    if (in && pos < NS) gbuf[wv][pos] = i;
    taken += (int)__popcll(mk);
  }
  int total = taken < NS ? taken : NS;
  int first = gbuf[wv][0];
  int* out = gidx + ((size_t)b * Q + q) * NS;
  for (int j = ln; j < NS; j += 64) out[j] = (j < total) ? gbuf[wv][j] : first;
}

// ---------------------------------------------------------------- MLP layers
// 256 threads, 64 sample-slots. A is transposed in LDS [k][m] (stride 68),
// thread tile = 4 samples x NC channels. W read from global (L1/L2 resident).
template<int K, int C, int SP, int NC>
DEVINL void mlp_layer(const float* __restrict__ W, const float* __restrict__ Bb,
                      const float* __restrict__ A, float* __restrict__ Bo, int t) {
  const int cg = t & 15, sg = t >> 4;
  const int m0 = sg * 4, c0 = cg * NC;
  float acc[4][NC];
#pragma unroll
  for (int j = 0; j < NC; ++j) {
    float b0 = Bb[c0 + j];
    acc[0][j] = b0; acc[1][j] = b0; acc[2][j] = b0; acc[3][j] = b0;
  }
  for (int k = 0; k < K; ++k) {
    const float4 a = *reinterpret_cast<const float4*>(A + k * SP + m0);
    const float* wr = W + (size_t)k * C + c0;
#pragma unroll
    for (int j = 0; j < NC; ++j) {
      float w = wr[j];
      acc[0][j] += a.x * w; acc[1][j] += a.y * w;
      acc[2][j] += a.z * w; acc[3][j] += a.w * w;
    }
  }
#pragma unroll
  for (int j = 0; j < NC; ++j) {
    float* o = Bo + (c0 + j) * SP + m0;
    o[0] = fmaxf(acc[0][j], 0.f); o[1] = fmaxf(acc[1][j], 0.f);
    o[2] = fmaxf(acc[2][j], 0.f); o[3] = fmaxf(acc[3][j], 0.f);
  }
}

template<int K, int C, int SP, int GPB, int NC>
DEVINL void mlp_layer3max(const float* __restrict__ W, const float* __restrict__ Bb,
                          const float* __restrict__ A, float* __restrict__ red,
                          float* __restrict__ out, int t) {
  const int cg = t & 15, sg = t >> 4;
  const int m0 = sg * 4, c0 = cg * NC;
  float acc[4][NC];
#pragma unroll
  for (int j = 0; j < NC; ++j) {
    float b0 = Bb[c0 + j];
    acc[0][j] = b0; acc[1][j] = b0; acc[2][j] = b0; acc[3][j] = b0;
  }
  for (int k = 0; k < K; ++k) {
    const float4 a = *reinterpret_cast<const float4*>(A + k * SP + m0);
    const float* wr = W + (size_t)k * C + c0;
#pragma unroll
    for (int j = 0; j < NC; ++j) {
      float w = wr[j];
      acc[0][j] += a.x * w; acc[1][j] += a.y * w;
      acc[2][j] += a.z * w; acc[3][j] += a.w * w;
    }
  }
#pragma unroll
  for (int j = 0; j < NC; ++j) {
    float mv = fmaxf(fmaxf(fmaxf(acc[0][j], acc[1][j]), fmaxf(acc[2][j], acc[3][j])), 0.f);
    red[sg * C + c0 + j] = mv;
  }
  __syncthreads();
  constexpr int SGPG = 16 / GPB;  // 4-sample tiles per group
  for (int u = t; u < GPB * C; u += 256) {
    int g = u / C, c = u - g * C;
    float mv = red[(g * SGPG) * C + c];
#pragma unroll
    for (int r = 1; r < SGPG; ++r) mv = fmaxf(mv, red[(g * SGPG + r) * C + c]);
    out[(size_t)g * C + c] = mv;
  }
}

// ---------------------------------------------------------------- fused SA (group+MLP+max)
// One block handles GPB groups (M*GPB == 64 sample slots).
template<int NPTS, int Q, int M, int GPB, int FD, int C1, int C2, int C3>
__global__ __launch_bounds__(256) void sa_mlp_kernel(
    const float* __restrict__ pts, const float* __restrict__ centers,
    const int* __restrict__ gidx, const float* __restrict__ feats,
    const float* __restrict__ W0, const float* __restrict__ B0,
    const float* __restrict__ W1, const float* __restrict__ B1,
    const float* __restrict__ W2, const float* __restrict__ B2,
    float* __restrict__ fout) {
  static_assert(M * GPB == 64, "");
  constexpr int K0 = 3 + FD;
  constexpr int SP = 68;
  constexpr int RA = (K0 > C2 ? K0 : C2);
  __shared__ float bufA[RA * SP];
  __shared__ float bufB[C1 * SP];
  __shared__ int idxs[64];
  __shared__ float ctr[GPB][3];
  const int t = threadIdx.x;
  const int blk = blockIdx.x;
  const int b = blk / (Q / GPB);
  const int q0 = (blk % (Q / GPB)) * GPB;
  if (t < GPB * 3) {
    int g = t / 3, c = t % 3;
    ctr[g][c] = centers[((size_t)b * Q + q0 + g) * 3 + c];
  }
  for (int m = t; m < 64; m += 256)
    idxs[m] = gidx[((size_t)b * Q + q0 + (m / M)) * M + (m % M)];
  __syncthreads();
  const float* pb = pts + (size_t)b * NPTS * 3;
  for (int m = t; m < 64; m += 256) {
    int g = m / M;
    int i = idxs[m];
    bufA[0 * SP + m] = pb[i * 3 + 0] - ctr[g][0];
    bufA[1 * SP + m] = pb[i * 3 + 1] - ctr[g][1];
    bufA[2 * SP + m] = pb[i * 3 + 2] - ctr[g][2];
  }
  if constexpr (FD > 0) {
    const int m = t >> 2, co = (t & 3) * (FD / 4);
    const float* src = feats + ((size_t)b * NPTS + idxs[m]) * FD + co;
#pragma unroll
    for (int j = 0; j < FD / 4; j += 4) {
      float4 v = *reinterpret_cast<const float4*>(src + j);
      bufA[(3 + co + j + 0) * SP + m] = v.x;
      bufA[(3 + co + j + 1) * SP + m] = v.y;
      bufA[(3 + co + j + 2) * SP + m] = v.z;
      bufA[(3 + co + j + 3) * SP + m] = v.w;
    }
  }
  __syncthreads();
  mlp_layer<K0, C1, SP, C1 / 16>(W0, B0, bufA, bufB, t);
  __syncthreads();
  mlp_layer<C1, C2, SP, C2 / 16>(W1, B1, bufB, bufA, t);
  __syncthreads();
  mlp_layer3max<C2, C3, SP, GPB, C3 / 16>(W2, B2, bufA, bufB,
                                          fout + ((size_t)b * Q + q0) * C3, t);
}

// ---------------------------------------------------------------- SA3 (global MLP)
// Per (batch, 64-channel tile). A staged to LDS transposed in K-chunks of 64.
template<int K, int CT, bool CONCAT, bool DOMAX>
__global__ __launch_bounds__(256) void sa3_kernel(
    const float* __restrict__ X, const float* __restrict__ X2,
    const float* __restrict__ W, const float* __restrict__ Bb,
    float* __restrict__ Out) {
  constexpr int M = 128, SP = 132, KC = 64;
  __shared__ float ldsA[KC * SP];
  __shared__ float red[32 * 64];
  const int t = threadIdx.x;
  const int b = blockIdx.x;
  const int c0b = blockIdx.y * 64;
  const int cg = t & 7, sg = t >> 3;  // 8 c-groups x 32 s-groups
  const int m0 = sg * 4;
  const int c0 = c0b + cg * 8;
  float acc[4][8];
#pragma unroll
  for (int j = 0; j < 8; ++j) {
    float v = Bb[c0 + j];
    acc[0][j] = v; acc[1][j] = v; acc[2][j] = v; acc[3][j] = v;
  }
  for (int kc = 0; kc < K; kc += KC) {
    const int kn = (K - kc < KC) ? (K - kc) : KC;
    __syncthreads();
    for (int u = t; u < M * KC; u += 256) {
      int m = u >> 6, kk = u & 63;
      if (kk < kn) {
        int k = kc + kk;
        float v;
        if constexpr (CONCAT) {
          v = (k < 3) ? X[((size_t)b * M + m) * 3 + k]
                      : X2[((size_t)b * M + m) * 256 + (k - 3)];
        } else {
          v = X[((size_t)b * M + m) * K + k];
        }
        ldsA[kk * SP + m] = v;
      }
    }
    __syncthreads();
    for (int kk = 0; kk < kn; ++kk) {
      const float4 a = *reinterpret_cast<const float4*>(ldsA + kk * SP + m0);
      const float* wr = W + (size_t)(kc + kk) * CT + c0;
#pragma unroll
      for (int j = 0; j < 8; ++j) {
        float w = wr[j];
        acc[0][j] += a.x * w; acc[1][j] += a.y * w;
        acc[2][j] += a.z * w; acc[3][j] += a.w * w;
      }
    }
  }
  if constexpr (!DOMAX) {
#pragma unroll
    for (int i = 0; i < 4; ++i) {
      float* o = Out + ((size_t)b * M + m0 + i) * CT + c0;
#pragma unroll
      for (int j = 0; j < 8; ++j) o[j] = fmaxf(acc[i][j], 0.f);
    }
  } else {
#pragma unroll
    for (int j = 0; j < 8; ++j) {
      float mv = fmaxf(fmaxf(fmaxf(acc[0][j], acc[1][j]), fmaxf(acc[2][j], acc[3][j])), 0.f);
      red[sg * 64 + cg * 8 + j] = mv;
    }
    __syncthreads();
    for (int c = t; c < 64; c += 256) {
      float mv = red[c];
#pragma unroll
      for (int r = 1; r < 32; ++r) mv = fmaxf(mv, red[r * 64 + c]);
      Out[(size_t)b * CT + c0b + c] = mv;
    }
  }
}

// ---------------------------------------------------------------- heads
__global__ __launch_bounds__(256) void heads_kernel(const float* __restrict__ feat,
                                                    const float* __restrict__ cw,
                                                    const float* __restrict__ cb,
                                                    const float* __restrict__ rw,
                                                    const float* __restrict__ rb,
                                                    float* __restrict__ out) {
  const int b = blockIdx.x, t = threadIdx.x;
  const float* fb = feat + (size_t)b * 1024;
  float a0 = 0, a1 = 0, a2 = 0, a3 = 0, a4 = 0;
  for (int k = t; k < 1024; k += 256) {
    float f = fb[k];
    a0 += f * cw[k];
    const float* r = rw + (size_t)k * 4;
    a1 += f * r[0]; a2 += f * r[1]; a3 += f * r[2]; a4 += f * r[3];
  }
#pragma unroll
  for (int m = 32; m >= 1; m >>= 1) {
    a0 += __shfl_xor(a0, m, 64); a1 += __shfl_xor(a1, m, 64);
    a2 += __shfl_xor(a2, m, 64); a3 += __shfl_xor(a3, m, 64);
    a4 += __shfl_xor(a4, m, 64);
  }
  __shared__ float red[4][5];
  const int wv = t >> 6, ln = t & 63;
  if (ln == 0) { red[wv][0] = a0; red[wv][1] = a1; red[wv][2] = a2; red[wv][3] = a3; red[wv][4] = a4; }
  __syncthreads();
  if (t == 0) {
    float s0 = red[0][0] + red[1][0] + red[2][0] + red[3][0];
    float s1 = red[0][1] + red[1][1] + red[2][1] + red[3][1];
    float s2 = red[0][2] + red[1][2] + red[2][2] + red[3][2];
    float s3 = red[0][3] + red[1][3] + red[2][3] + red[3][3];
    float s4 = red[0][4] + red[1][4] + red[2][4] + red[3][4];
    out[b] = s0 + cb[0];
    out[32 + b * 4 + 0] = s1 + rb[0];
    out[32 + b * 4 + 1] = s2 + rb[1];
    out[32 + b * 4 + 2] = s3 + rb[2];
    out[32 + b * 4 + 3] = s4 + rb[3];
  }
}

// ---------------------------------------------------------------- launch
extern "C" void kernel_launch(void* const* d_in, const int* in_sizes, int n_in,
                              void* d_out, int out_size, void* d_ws, size_t ws_size,
                              hipStream_t stream) {
  (void)in_sizes; (void)n_in; (void)out_size; (void)ws_size;
  const float* xyz  = (const float*)d_in[0];
  const float* s1w0 = (const float*)d_in[1];  const float* s1b0 = (const float*)d_in[2];
  const float* s1w1 = (const float*)d_in[3];  const float* s1b1 = (const float*)d_in[4];
  const float* s1w2 = (const float*)d_in[5];  const float* s1b2 = (const float*)d_in[6];
  const float* s2w0 = (const float*)d_in[7];  const float* s2b0 = (const float*)d_in[8];
  const float* s2w1 = (const float*)d_in[9];  const float* s2b1 = (const float*)d_in[10];
  const float* s2w2 = (const float*)d_in[11]; const float* s2b2 = (const float*)d_in[12];
  const float* s3w0 = (const float*)d_in[13]; const float* s3b0 = (const float*)d_in[14];
  const float* s3w1 = (const float*)d_in[15]; const float* s3b1 = (const float*)d_in[16];
  const float* s3w2 = (const float*)d_in[17]; const float* s3b2 = (const float*)d_in[18];
  const float* clsw = (const float*)d_in[19]; const float* clsb = (const float*)d_in[20];
  const float* regw = (const float*)d_in[21]; const float* regb = (const float*)d_in[22];

  char* ws = (char*)d_ws;
  float* nx1   = (float*)(ws + 0);          // 32*512*3
  int*   gidx1 = (int*)  (ws + 196608);     // 32*512*32
  float* f1    = (float*)(ws + 2293760);    // 32*512*128
  float* nx2   = (float*)(ws + 10682368);   // 32*128*3
  int*   gidx2 = (int*)  (ws + 10731520);   // 32*128*64
  float* f2    = (float*)(ws + 11780096);   // 32*128*256
  float* h1    = (float*)(ws + 15974400);   // 32*128*256
  float* h2    = (float*)(ws + 20168704);   // 32*128*512
  float* feat  = (float*)(ws + 28557312);   // 32*1024

  const float r21 = (float)(0.2 * 0.2);
  const float r22 = (float)(0.4 * 0.4);

  fps_kernel<4096, 512><<<32, 256, 0, stream>>>(xyz, nx1);
  bq_kernel<4096, 32><<<4096, 256, 0, stream>>>(xyz, nx1, gidx1, 512, r21);
  sa_mlp_kernel<4096, 512, 32, 2, 0, 64, 64, 128><<<8192, 256, 0, stream>>>(
      xyz, nx1, gidx1, (const float*)nullptr, s1w0, s1b0, s1w1, s1b1, s1w2, s1b2, f1);
  fps_kernel<512, 128><<<32, 256, 0, stream>>>(nx1, nx2);
  bq_kernel<512, 64><<<1024, 256, 0, stream>>>(nx1, nx2, gidx2, 128, r22);
  sa_mlp_kernel<512, 128, 64, 1, 128, 128, 128, 256><<<4096, 256, 0, stream>>>(
      nx1, nx2, gidx2, f1, s2w0, s2b0, s2w1, s2b1, s2w2, s2b2, f2);
  sa3_kernel<259, 256, true, false><<<dim3(32, 4), 256, 0, stream>>>(nx2, f2, s3w0, s3b0, h1);
  sa3_kernel<256, 512, false, false><<<dim3(32, 8), 256, 0, stream>>>(h1, nullptr, s3w1, s3b1, h2);
  sa3_kernel<512, 1024, false, true><<<dim3(32, 16), 256, 0, stream>>>(h2, nullptr, s3w2, s3b2, feat);
  heads_kernel<<<32, 256, 0, stream>>>(feat, clsw, clsb, regw, regb, (float*)d_out);
}

// Round 2
// 1186.378 us; speedup vs baseline: 1.5466x; 1.5466x over previous
//
#include <hip/hip_runtime.h>

#define DEVINL __device__ __forceinline__

typedef __attribute__((ext_vector_type(8))) short bf16x8;
typedef __attribute__((ext_vector_type(8))) unsigned short u16x8;
typedef __attribute__((ext_vector_type(4))) float f32x4;

// RNE f32 -> bf16 bits (no NaN handling needed for this workload)
DEVINL unsigned short f2bh(float f){
  unsigned u = __float_as_uint(f);
  return (unsigned short)((u + 0x7FFFu + ((u >> 16) & 1u)) >> 16);
}
DEVINL float bh2f(unsigned short h){ return __uint_as_float(((unsigned)h) << 16); }

// ---------------------------------------------------------------- FPS (unchanged, exact f32)
template<int N, int NP>
__global__ __launch_bounds__(256) void fps_kernel(const float* __restrict__ xyz,
                                                  float* __restrict__ nxyz) {
  constexpr int PTS = N / 256;
  const int b = blockIdx.x, t = threadIdx.x;
  __shared__ float xs[N], ys[N], zs[N];
  __shared__ float swv[4];
  __shared__ int swi[4];
  __shared__ int sfar;
  float px[PTS], py[PTS], pz[PTS], dst[PTS];
  const float* base = xyz + (size_t)b * N * 3;
#pragma unroll
  for (int j = 0; j < PTS; ++j) {
    int i = t + j * 256;
    float x = base[i * 3 + 0], y = base[i * 3 + 1], z = base[i * 3 + 2];
    px[j] = x; py[j] = y; pz[j] = z;
    xs[i] = x; ys[i] = y; zs[i] = z;
    dst[j] = 1e10f;
  }
  __syncthreads();
  int far = 0;
  const int wv = t >> 6, ln = t & 63;
  for (int s = 0; s < NP; ++s) {
    float cx = xs[far], cy = ys[far], cz = zs[far];
    if (t == 0) {
      float* o = nxyz + ((size_t)b * NP + s) * 3;
      o[0] = cx; o[1] = cy; o[2] = cz;
    }
    float bv = -1.f; int bi = 0;
#pragma unroll
    for (int j = 0; j < PTS; ++j) {
      float dx = __fsub_rn(px[j], cx), dy = __fsub_rn(py[j], cy), dz = __fsub_rn(pz[j], cz);
      float d = __fadd_rn(__fadd_rn(__fmul_rn(dx, dx), __fmul_rn(dy, dy)), __fmul_rn(dz, dz));
      float nd = fminf(dst[j], d);
      dst[j] = nd;
      int i = t + j * 256;
      if (nd > bv) { bv = nd; bi = i; }
    }
#pragma unroll
    for (int m = 32; m >= 1; m >>= 1) {
      float ov = __shfl_xor(bv, m, 64);
      int   oi = __shfl_xor(bi, m, 64);
      if (ov > bv || (ov == bv && oi < bi)) { bv = ov; bi = oi; }
    }
    if (ln == 0) { swv[wv] = bv; swi[wv] = bi; }
    __syncthreads();
    if (t == 0) {
      float v = swv[0]; int ii = swi[0];
#pragma unroll
      for (int q = 1; q < 4; ++q)
        if (swv[q] > v || (swv[q] == v && swi[q] < ii)) { v = swv[q]; ii = swi[q]; }
      sfar = ii;
    }
    __syncthreads();
    far = sfar;
  }
}

// ---------------------------------------------------------------- ball query (unchanged)
template<int N, int NS>
__global__ __launch_bounds__(256) void bq_kernel(const float* __restrict__ pts,
                                                 const float* __restrict__ centers,
                                                 int* __restrict__ gidx, int Q, float r2) {
  const int wv = threadIdx.x >> 6, ln = threadIdx.x & 63;
  const int g = blockIdx.x * 4 + wv;
  const int b = g / Q, q = g % Q;
  const float* pb = pts + (size_t)b * N * 3;
  const float* c = centers + ((size_t)b * Q + q) * 3;
  const float cx = c[0], cy = c[1], cz = c[2];
  __shared__ int gbuf[4][NS];
  int taken = 0;
  for (int base = 0; base < N; base += 64) {
    if (taken >= NS) break;
    int i = base + ln;
    float dx = __fsub_rn(pb[i * 3 + 0], cx), dy = __fsub_rn(pb[i * 3 + 1], cy),
          dz = __fsub_rn(pb[i * 3 + 2], cz);
    float d = __fadd_rn(__fadd_rn(__fmul_rn(dx, dx), __fmul_rn(dy, dy)), __fmul_rn(dz, dz));
    bool in = (d <= r2);
    unsigned long long mk = __ballot(in);
    int rank = __popcll(mk & ((1ull << ln) - 1ull));
    int pos = taken + rank;
    if (in && pos < NS) gbuf[wv][pos] = i;
    taken += (int)__popcll(mk);
  }
  int total = taken < NS ? taken : NS;
  int first = gbuf[wv][0];
  int* out = gidx + ((size_t)b * Q + q) * NS;
  for (int j = ln; j < NS; j += 64) out[j] = (j < total) ? gbuf[wv][j] : first;
}

// ---------------------------------------------------------------- weight prep: transpose + hi/lo split
// W[row0+k][n] (f32) -> hi/lo [n][k] bf16 bits. Run once per weight matrix.
__global__ __launch_bounds__(256) void wprep_kernel(const float* __restrict__ W, int K, int N,
                                                    int row0, unsigned short* __restrict__ hi,
                                                    unsigned short* __restrict__ lo) {
  int idx = blockIdx.x * 256 + threadIdx.x;
  if (idx >= K * N) return;
  int k = idx / N, n = idx - k * N;
  float v = W[(size_t)(row0 + k) * N + n];
  unsigned short h = f2bh(v);
  hi[(size_t)n * K + k] = h;
  lo[(size_t)n * K + k] = f2bh(v - bh2f(h));
}

// ---------------------------------------------------------------- split-bf16 MFMA layer
// A (f32, LDS, [64][AS]) x W (K x N, prepped transposed hi/lo in global) -> acc (f32, no bias).
// Each wave owns rows [wv*16, wv*16+16). 3 MFMAs per tile: Ah*Wh + Al*Wh + Ah*Wl.
template<int K, int N, int AS, int WS, bool XYZC>
DEVINL void do_layer(const unsigned short* __restrict__ Ghi, const unsigned short* __restrict__ Glo,
                     const float* __restrict__ Wxyz,
                     const float* __restrict__ A, unsigned short* __restrict__ Whi,
                     unsigned short* __restrict__ Wlo, const float* __restrict__ sxyz,
                     f32x4* acc, int t) {
  constexpr int KT = K / 32;
  constexpr int NCH = N / 64;
  const int l = t & 63, wv = t >> 6;
  bf16x8 ahi[KT], alo[KT];
  {
    const int row = wv * 16 + (l & 15);
    const float* ap = A + row * AS + (l >> 4) * 8;
#pragma unroll
    for (int kt = 0; kt < KT; ++kt) {
      float4 v0 = *reinterpret_cast<const float4*>(ap + kt * 32);
      float4 v1 = *reinterpret_cast<const float4*>(ap + kt * 32 + 4);
      float f[8] = {v0.x, v0.y, v0.z, v0.w, v1.x, v1.y, v1.z, v1.w};
      bf16x8 h, lo2;
#pragma unroll
      for (int j = 0; j < 8; ++j) {
        unsigned short hb = f2bh(f[j]);
        h[j] = (short)hb;
        lo2[j] = (short)f2bh(f[j] - bh2f(hb));
      }
      ahi[kt] = h; alo[kt] = lo2;
    }
  }
#pragma unroll
  for (int i = 0; i < N / 16; ++i) acc[i] = f32x4{0.f, 0.f, 0.f, 0.f};

#pragma unroll
  for (int c = 0; c < NCH; ++c) {
    __syncthreads();  // all waves done reading previous Wt contents
    {
      constexpr int K8 = K / 8;
      for (int u = t; u < 64 * K8; u += 256) {
        int nn = u / K8, k8 = (u - nn * K8) * 8;
        *reinterpret_cast<u16x8*>(Whi + nn * WS + k8) =
            *reinterpret_cast<const u16x8*>(Ghi + (size_t)(c * 64 + nn) * K + k8);
        *reinterpret_cast<u16x8*>(Wlo + nn * WS + k8) =
            *reinterpret_cast<const u16x8*>(Glo + (size_t)(c * 64 + nn) * K + k8);
      }
    }
    __syncthreads();
#pragma unroll
    for (int ct = 0; ct < 4; ++ct) {
      const unsigned short* wp = Whi + (ct * 16 + (l & 15)) * WS + (l >> 4) * 8;
      const unsigned short* wq = Wlo + (ct * 16 + (l & 15)) * WS + (l >> 4) * 8;
      f32x4 a = acc[c * 4 + ct];
#pragma unroll
      for (int kt = 0; kt < KT; ++kt) {
        bf16x8 wh = *reinterpret_cast<const bf16x8*>(wp + kt * 32);
        bf16x8 wl = *reinterpret_cast<const bf16x8*>(wq + kt * 32);
        a = __builtin_amdgcn_mfma_f32_16x16x32_bf16(ahi[kt], wh, a, 0, 0, 0);
        a = __builtin_amdgcn_mfma_f32_16x16x32_bf16(alo[kt], wh, a, 0, 0, 0);
        a = __builtin_amdgcn_mfma_f32_16x16x32_bf16(ahi[kt], wl, a, 0, 0, 0);
      }
      acc[c * 4 + ct] = a;
    }
  }
  if constexpr (XYZC) {  // exact f32 correction for the 3 xyz input dims (W rows 0..2)
    float xr[4][3];
#pragma unroll
    for (int r = 0; r < 4; ++r) {
      int row = wv * 16 + (l >> 4) * 4 + r;
      xr[r][0] = sxyz[row * 4 + 0];
      xr[r][1] = sxyz[row * 4 + 1];
      xr[r][2] = sxyz[row * 4 + 2];
    }
#pragma unroll
    for (int gt = 0; gt < N / 16; ++gt) {
      int col = gt * 16 + (l & 15);
      float w0 = Wxyz[col], w1 = Wxyz[N + col], w2 = Wxyz[2 * N + col];
#pragma unroll
      for (int r = 0; r < 4; ++r)
        acc[gt][r] += xr[r][0] * w0 + xr[r][1] * w1 + xr[r][2] * w2;
    }
  }
}

// ---------------------------------------------------------------- fused SA stage (gather + 3 layers + maxpool)
template<int NPTS, int Q, int M, int GPB, int FD, int C1, int C2, int C3>
__global__ __launch_bounds__(256) void sa_mfma_kernel(
    const float* __restrict__ pts, const float* __restrict__ centers,
    const int* __restrict__ gidx, const float* __restrict__ feats,
    const float* __restrict__ W0, const float* __restrict__ B0,
    const unsigned short* __restrict__ G0h, const unsigned short* __restrict__ G0l,
    const unsigned short* __restrict__ G1h, const unsigned short* __restrict__ G1l,
    const float* __restrict__ B1,
    const unsigned short* __restrict__ G2h, const unsigned short* __restrict__ G2l,
    const float* __restrict__ B2,
    float* __restrict__ fout) {
  static_assert(M * GPB == 64, "");
  constexpr int MK1 = (FD > C1 ? FD : C1);
  constexpr int MAXK = (MK1 > C2 ? MK1 : C2);
  constexpr int AS = MAXK + 8;
  constexpr int WS = MAXK + 8;
  __shared__ __align__(16) float A[64 * AS];
  __shared__ __align__(16) unsigned short Whi[64 * WS];
  __shared__ __align__(16) unsigned short Wlo[64 * WS];
  __shared__ float sxyz[64 * 4];
  __shared__ int idxs[64];
  __shared__ float ctr[GPB][4];
  __shared__ float red[4][C3];

  const int t = threadIdx.x;
  const int blk = blockIdx.x;
  const int b = blk / (Q / GPB);
  const int q0 = (blk % (Q / GPB)) * GPB;
  const int l = t & 63, wv = t >> 6;

  if (t < GPB * 3) {
    int g = t / 3, c2 = t % 3;
    ctr[g][c2] = centers[((size_t)b * Q + q0 + g) * 3 + c2];
  }
  for (int m = t; m < 64; m += 256)
    idxs[m] = gidx[((size_t)b * Q + q0 + (m / M)) * M + (m % M)];
  __syncthreads();
  const float* pb = pts + (size_t)b * NPTS * 3;
  for (int m = t; m < 64; m += 256) {
    int g = m / M, i = idxs[m];
    sxyz[m * 4 + 0] = pb[i * 3 + 0] - ctr[g][0];
    sxyz[m * 4 + 1] = pb[i * 3 + 1] - ctr[g][1];
    sxyz[m * 4 + 2] = pb[i * 3 + 2] - ctr[g][2];
  }
  if constexpr (FD > 0) {
    const int m = t >> 2, co = (t & 3) * (FD / 4);
    const float* src = feats + ((size_t)b * NPTS + idxs[m]) * FD + co;
    float* dst = A + m * AS + co;
#pragma unroll
    for (int j = 0; j < FD / 4; j += 4)
      *reinterpret_cast<float4*>(dst + j) = *reinterpret_cast<const float4*>(src + j);
  }
  __syncthreads();

  f32x4 acc[C3 / 16];

  if constexpr (FD == 0) {
    // layer0: 3 -> C1 in exact f32 VALU (K=3 too small for MFMA)
    for (int u = t; u < 64 * C1; u += 256) {
      int m = u / C1, c2 = u - m * C1;
      float v = B0[c2] + sxyz[m * 4 + 0] * W0[0 * C1 + c2]
                       + sxyz[m * 4 + 1] * W0[1 * C1 + c2]
                       + sxyz[m * 4 + 2] * W0[2 * C1 + c2];
      A[m * AS + c2] = fmaxf(v, 0.f);
    }
    __syncthreads();
  } else {
    do_layer<FD, C1, AS, WS, true>(G0h, G0l, W0, A, Whi, Wlo, sxyz, acc, t);
#pragma unroll
    for (int gt = 0; gt < C1 / 16; ++gt) {
      int col = gt * 16 + (l & 15);
      float bia = B0[col];
#pragma unroll
      for (int r = 0; r < 4; ++r)
        A[(wv * 16 + (l >> 4) * 4 + r) * AS + col] = fmaxf(acc[gt][r] + bia, 0.f);
    }
  }

  do_layer<C1, C2, AS, WS, false>(G1h, G1l, nullptr, A, Whi, Wlo, sxyz, acc, t);
#pragma unroll
  for (int gt = 0; gt < C2 / 16; ++gt) {
    int col = gt * 16 + (l & 15);
    float bia = B1[col];
#pragma unroll
    for (int r = 0; r < 4; ++r)
      A[(wv * 16 + (l >> 4) * 4 + r) * AS + col] = fmaxf(acc[gt][r] + bia, 0.f);
  }

  do_layer<C2, C3, AS, WS, false>(G2h, G2l, nullptr, A, Whi, Wlo, sxyz, acc, t);
  // maxpool epilogue: max over rows within each group, then +bias, relu
#pragma unroll
  for (int gt = 0; gt < C3 / 16; ++gt) {
    int col = gt * 16 + (l & 15);
    float v = fmaxf(fmaxf(acc[gt][0], acc[gt][1]), fmaxf(acc[gt][2], acc[gt][3]));
    v = fmaxf(v, __shfl_xor(v, 16, 64));
    v = fmaxf(v, __shfl_xor(v, 32, 64));
    if (l < 16) red[wv][col] = v + B2[col];
  }
  __syncthreads();
  constexpr int WPG = 4 / GPB;
  for (int u = t; u < GPB * C3; u += 256) {
    int g = u / C3, c2 = u - g * C3;
    float v = red[g * WPG][c2];
#pragma unroll
    for (int w = 1; w < WPG; ++w) v = fmaxf(v, red[g * WPG + w][c2]);
    fout[((size_t)b * Q + q0 + g) * C3 + c2] = fmaxf(v, 0.f);
  }
}

// ---------------------------------------------------------------- SA3 (global MLP, f32 — convert later if hot)
template<int K, int CT, bool CONCAT, bool DOMAX>
__global__ __launch_bounds__(256) void sa3_kernel(
    const float* __restrict__ X, const float* __restrict__ X2,
    const float* __restrict__ W, const float* __restrict__ Bb,
    float* __restrict__ Out) {
  constexpr int M = 128, SP = 132, KC = 64;
  __shared__ float ldsA[KC * SP];
  __shared__ float red[32 * 64];
  const int t = threadIdx.x;
  const int b = blockIdx.x;
  const int c0b = blockIdx.y * 64;
  const int cg = t & 7, sg = t >> 3;
  const int m0 = sg * 4;
  const int c0 = c0b + cg * 8;
  float acc[4][8];
#pragma unroll
  for (int j = 0; j < 8; ++j) {
    float v = Bb[c0 + j];
    acc[0][j] = v; acc[1][j] = v; acc[2][j] = v; acc[3][j] = v;
  }
  for (int kc = 0; kc < K; kc += KC) {
    const int kn = (K - kc < KC) ? (K - kc) : KC;
    __syncthreads();
    for (int u = t; u < M * KC; u += 256) {
      int m = u >> 6, kk = u & 63;
      if (kk < kn) {
        int k = kc + kk;
        float v;
        if constexpr (CONCAT) {
          v = (k < 3) ? X[((size_t)b * M + m) * 3 + k]
                      : X2[((size_t)b * M + m) * 256 + (k - 3)];
        } else {
          v = X[((size_t)b * M + m) * K + k];
        }
        ldsA[kk * SP + m] = v;
      }
    }
    __syncthreads();
    for (int kk = 0; kk < kn; ++kk) {
      const float4 a = *reinterpret_cast<const float4*>(ldsA + kk * SP + m0);
      const float* wr = W + (size_t)(kc + kk) * CT + c0;
#pragma unroll
      for (int j = 0; j < 8; ++j) {
        float w = wr[j];
        acc[0][j] += a.x * w; acc[1][j] += a.y * w;
        acc[2][j] += a.z * w; acc[3][j] += a.w * w;
      }
    }
  }
  if constexpr (!DOMAX) {
#pragma unroll
    for (int i = 0; i < 4; ++i) {
      float* o = Out + ((size_t)b * M + m0 + i) * CT + c0;
#pragma unroll
      for (int j = 0; j < 8; ++j) o[j] = fmaxf(acc[i][j], 0.f);
    }
  } else {
#pragma unroll
    for (int j = 0; j < 8; ++j) {
      float mv = fmaxf(fmaxf(fmaxf(acc[0][j], acc[1][j]), fmaxf(acc[2][j], acc[3][j])), 0.f);
      red[sg * 64 + cg * 8 + j] = mv;
    }
    __syncthreads();
    for (int c = t; c < 64; c += 256) {
      float mv = red[c];
#pragma unroll
      for (int r = 1; r < 32; ++r) mv = fmaxf(mv, red[r * 64 + c]);
      Out[(size_t)b * CT + c0b + c] = mv;
    }
  }
}

// ---------------------------------------------------------------- heads
__global__ __launch_bounds__(256) void heads_kernel(const float* __restrict__ feat,
                                                    const float* __restrict__ cw,
                                                    const float* __restrict__ cb,
                                                    const float* __restrict__ rw,
                                                    const float* __restrict__ rb,
                                                    float* __restrict__ out) {
  const int b = blockIdx.x, t = threadIdx.x;
  const float* fb = feat + (size_t)b * 1024;
  float a0 = 0, a1 = 0, a2 = 0, a3 = 0, a4 = 0;
  for (int k = t; k < 1024; k += 256) {
    float f = fb[k];
    a0 += f * cw[k];
    const float* r = rw + (size_t)k * 4;
    a1 += f * r[0]; a2 += f * r[1]; a3 += f * r[2]; a4 += f * r[3];
  }
#pragma unroll
  for (int m = 32; m >= 1; m >>= 1) {
    a0 += __shfl_xor(a0, m, 64); a1 += __shfl_xor(a1, m, 64);
    a2 += __shfl_xor(a2, m, 64); a3 += __shfl_xor(a3, m, 64);
    a4 += __shfl_xor(a4, m, 64);
  }
  __shared__ float red[4][5];
  const int wv = t >> 6, ln = t & 63;
  if (ln == 0) { red[wv][0] = a0; red[wv][1] = a1; red[wv][2] = a2; red[wv][3] = a3; red[wv][4] = a4; }
  __syncthreads();
  if (t == 0) {
    float s0 = red[0][0] + red[1][0] + red[2][0] + red[3][0];
    float s1 = red[0][1] + red[1][1] + red[2][1] + red[3][1];
    float s2 = red[0][2] + red[1][2] + red[2][2] + red[3][2];
    float s3 = red[0][3] + red[1][3] + red[2][3] + red[3][3];
    float s4 = red[0][4] + red[1][4] + red[2][4] + red[3][4];
    out[b] = s0 + cb[0];
    out[32 + b * 4 + 0] = s1 + rb[0];
    out[32 + b * 4 + 1] = s2 + rb[1];
    out[32 + b * 4 + 2] = s3 + rb[2];
    out[32 + b * 4 + 3] = s4 + rb[3];
  }
}

// ---------------------------------------------------------------- launch
extern "C" void kernel_launch(void* const* d_in, const int* in_sizes, int n_in,
                              void* d_out, int out_size, void* d_ws, size_t ws_size,
                              hipStream_t stream) {
  (void)in_sizes; (void)n_in; (void)out_size; (void)ws_size;
  const float* xyz  = (const float*)d_in[0];
  const float* s1w0 = (const float*)d_in[1];  const float* s1b0 = (const float*)d_in[2];
  const float* s1w1 = (const float*)d_in[3];  const float* s1b1 = (const float*)d_in[4];
  const float* s1w2 = (const float*)d_in[5];  const float* s1b2 = (const float*)d_in[6];
  const float* s2w0 = (const float*)d_in[7];  const float* s2b0 = (const float*)d_in[8];
  const float* s2w1 = (const float*)d_in[9];  const float* s2b1 = (const float*)d_in[10];
  const float* s2w2 = (const float*)d_in[11]; const float* s2b2 = (const float*)d_in[12];
  const float* s3w0 = (const float*)d_in[13]; const float* s3b0 = (const float*)d_in[14];
  const float* s3w1 = (const float*)d_in[15]; const float* s3b1 = (const float*)d_in[16];
  const float* s3w2 = (const float*)d_in[17]; const float* s3b2 = (const float*)d_in[18];
  const float* clsw = (const float*)d_in[19]; const float* clsb = (const float*)d_in[20];
  const float* regw = (const float*)d_in[21]; const float* regb = (const float*)d_in[22];

  char* ws = (char*)d_ws;
  float* nx1   = (float*)(ws + 0);          // 32*512*3
  int*   gidx1 = (int*)  (ws + 196608);     // 32*512*32
  float* f1    = (float*)(ws + 2293760);    // 32*512*128
  float* nx2   = (float*)(ws + 10682368);   // 32*128*3
  int*   gidx2 = (int*)  (ws + 10731520);   // 32*128*64
  float* f2    = (float*)(ws + 11780096);   // 32*128*256
  float* h1    = (float*)(ws + 15974400);   // 32*128*256
  float* h2    = (float*)(ws + 20168704);   // 32*128*512
  float* feat  = (float*)(ws + 28557312);   // 32*1024

  // Prepped hi/lo transposed weights live in the h2 region: written by wprep at
  // the start, consumed by sa_mfma (SA1/SA2), then legitimately overwritten by
  // sa3's h2 output afterwards. Deterministic: rewritten every call.
  unsigned short* wt = (unsigned short*)(ws + 20168704);
  unsigned short* g11h = wt;            // 64*64
  unsigned short* g11l = wt + 4096;
  unsigned short* g12h = wt + 8192;     // 128*64
  unsigned short* g12l = wt + 16384;
  unsigned short* g20h = wt + 24576;    // 128*128 (rows 3..130 of s2w0)
  unsigned short* g20l = wt + 40960;
  unsigned short* g21h = wt + 57344;    // 128*128
  unsigned short* g21l = wt + 73728;
  unsigned short* g22h = wt + 90112;    // 256*128
  unsigned short* g22l = wt + 122880;   // ends at 155648 shorts = 311296 B < 8 MB

  const float r21 = (float)(0.2 * 0.2);
  const float r22 = (float)(0.4 * 0.4);

  wprep_kernel<<<16, 256, 0, stream>>>(s1w1, 64, 64, 0, g11h, g11l);
  wprep_kernel<<<32, 256, 0, stream>>>(s1w2, 64, 128, 0, g12h, g12l);
  wprep_kernel<<<64, 256, 0, stream>>>(s2w0, 128, 128, 3, g20h, g20l);
  wprep_kernel<<<64, 256, 0, stream>>>(s2w1, 128, 128, 0, g21h, g21l);
  wprep_kernel<<<128, 256, 0, stream>>>(s2w2, 128, 256, 0, g22h, g22l);

  fps_kernel<4096, 512><<<32, 256, 0, stream>>>(xyz, nx1);
  bq_kernel<4096, 32><<<4096, 256, 0, stream>>>(xyz, nx1, gidx1, 512, r21);
  sa_mfma_kernel<4096, 512, 32, 2, 0, 64, 64, 128><<<8192, 256, 0, stream>>>(
      xyz, nx1, gidx1, (const float*)nullptr, s1w0, s1b0,
      nullptr, nullptr, g11h, g11l, s1b1, g12h, g12l, s1b2, f1);
  fps_kernel<512, 128><<<32, 256, 0, stream>>>(nx1, nx2);
  bq_kernel<512, 64><<<1024, 256, 0, stream>>>(nx1, nx2, gidx2, 128, r22);
  sa_mfma_kernel<512, 128, 64, 1, 128, 128, 128, 256><<<4096, 256, 0, stream>>>(
      nx1, nx2, gidx2, f1, s2w0, s2b0,
      g20h, g20l, g21h, g21l, s2b1, g22h, g22l, s2b2, f2);
  sa3_kernel<259, 256, true, false><<<dim3(32, 4), 256, 0, stream>>>(nx2, f2, s3w0, s3b0, h1);
  sa3_kernel<256, 512, false, false><<<dim3(32, 8), 256, 0, stream>>>(h1, nullptr, s3w1, s3b1, h2);
  sa3_kernel<512, 1024, false, true><<<dim3(32, 16), 256, 0, stream>>>(h2, nullptr, s3w2, s3b2, feat);
  heads_kernel<<<32, 256, 0, stream>>>(feat, clsw, clsb, regw, regb, (float*)d_out);
}

// Round 3
// 1133.498 us; speedup vs baseline: 1.6187x; 1.0467x over previous
//
#include <hip/hip_runtime.h>

#define DEVINL __device__ __forceinline__

typedef __attribute__((ext_vector_type(8))) short bf16x8;
typedef __attribute__((ext_vector_type(8))) unsigned short u16x8;
typedef __attribute__((ext_vector_type(4))) float f32x4;

// RNE f32 -> bf16 bits (no NaN handling needed for this workload)
DEVINL unsigned short f2bh(float f){
  unsigned u = __float_as_uint(f);
  return (unsigned short)((u + 0x7FFFu + ((u >> 16) & 1u)) >> 16);
}
DEVINL float bh2f(unsigned short h){ return __uint_as_float(((unsigned)h) << 16); }

// ---------------------------------------------------------------- FPS
// Latency-optimized: one barrier per step (double-buffered wave candidates),
// all-thread redundant final reduce (no thread-0 funnel, no 2nd barrier).
// NT=64 specialization has no barriers at all inside the loop.
// Distance arithmetic and tie-break identical to the verified r1 version.
template<int N, int NP, int NT>
__global__ __launch_bounds__(NT) void fps_kernel(const float* __restrict__ xyz,
                                                 float* __restrict__ nxyz) {
  constexpr int PTS = N / NT;
  constexpr int NW = NT / 64;
  const int b = blockIdx.x, t = threadIdx.x;
  __shared__ float xs[N], ys[N], zs[N];
  __shared__ __align__(16) float svv[2][(NW > 1 ? NW : 1)];
  __shared__ __align__(16) int   svi[2][(NW > 1 ? NW : 1)];
  float px[PTS], py[PTS], pz[PTS], dst[PTS];
  const float* base = xyz + (size_t)b * N * 3;
#pragma unroll
  for (int j = 0; j < PTS; ++j) {
    int i = t + j * NT;
    float x = base[i * 3 + 0], y = base[i * 3 + 1], z = base[i * 3 + 2];
    px[j] = x; py[j] = y; pz[j] = z;
    xs[i] = x; ys[i] = y; zs[i] = z;
    dst[j] = 1e10f;
  }
  __syncthreads();
  int far = 0;
  const int wv = t >> 6, ln = t & 63;
  for (int s = 0; s < NP; ++s) {
    float cx = xs[far], cy = ys[far], cz = zs[far];
    if (t == 0) {
      float* o = nxyz + ((size_t)b * NP + s) * 3;
      o[0] = cx; o[1] = cy; o[2] = cz;
    }
    float bv = -1.f; int bi = 0;
#pragma unroll
    for (int j = 0; j < PTS; ++j) {
      // no-fma, left-to-right: matches numpy elementwise + sum order
      float dx = __fsub_rn(px[j], cx), dy = __fsub_rn(py[j], cy), dz = __fsub_rn(pz[j], cz);
      float d = __fadd_rn(__fadd_rn(__fmul_rn(dx, dx), __fmul_rn(dy, dy)), __fmul_rn(dz, dz));
      float nd = fminf(dst[j], d);
      dst[j] = nd;
      int i = t + j * NT;
      if (nd > bv) { bv = nd; bi = i; }  // ascending i per thread -> first max kept
    }
#pragma unroll
    for (int m = 1; m <= 32; m <<= 1) {
      float ov = __shfl_xor(bv, m, 64);
      int   oi = __shfl_xor(bi, m, 64);
      if (ov > bv || (ov == bv && oi < bi)) { bv = ov; bi = oi; }
    }
    if constexpr (NW == 1) {
      far = bi;  // butterfly left the wave-wide result in every lane
    } else {
      const int p = s & 1;
      if (ln == 0) { svv[p][wv] = bv; svi[p][wv] = bi; }
      __syncthreads();
      float v = svv[p][0]; int ii = svi[p][0];
#pragma unroll
      for (int q = 1; q < NW; ++q) {
        float qv = svv[p][q]; int qi = svi[p][q];
        if (qv > v || (qv == v && qi < ii)) { v = qv; ii = qi; }
      }
      far = ii;
    }
  }
}

// ---------------------------------------------------------------- ball query (unchanged)
template<int N, int NS>
__global__ __launch_bounds__(256) void bq_kernel(const float* __restrict__ pts,
                                                 const float* __restrict__ centers,
                                                 int* __restrict__ gidx, int Q, float r2) {
  const int wv = threadIdx.x >> 6, ln = threadIdx.x & 63;
  const int g = blockIdx.x * 4 + wv;
  const int b = g / Q, q = g % Q;
  const float* pb = pts + (size_t)b * N * 3;
  const float* c = centers + ((size_t)b * Q + q) * 3;
  const float cx = c[0], cy = c[1], cz = c[2];
  __shared__ int gbuf[4][NS];
  int taken = 0;
  for (int base = 0; base < N; base += 64) {
    if (taken >= NS) break;
    int i = base + ln;
    float dx = __fsub_rn(pb[i * 3 + 0], cx), dy = __fsub_rn(pb[i * 3 + 1], cy),
          dz = __fsub_rn(pb[i * 3 + 2], cz);
    float d = __fadd_rn(__fadd_rn(__fmul_rn(dx, dx), __fmul_rn(dy, dy)), __fmul_rn(dz, dz));
    bool in = (d <= r2);
    unsigned long long mk = __ballot(in);
    int rank = __popcll(mk & ((1ull << ln) - 1ull));
    int pos = taken + rank;
    if (in && pos < NS) gbuf[wv][pos] = i;
    taken += (int)__popcll(mk);
  }
  int total = taken < NS ? taken : NS;
  int first = gbuf[wv][0];
  int* out = gidx + ((size_t)b * Q + q) * NS;
  for (int j = ln; j < NS; j += 64) out[j] = (j < total) ? gbuf[wv][j] : first;
}

// ---------------------------------------------------------------- weight prep: transpose + hi/lo split
__global__ __launch_bounds__(256) void wprep_kernel(const float* __restrict__ W, int K, int N,
                                                    int row0, unsigned short* __restrict__ hi,
                                                    unsigned short* __restrict__ lo) {
  int idx = blockIdx.x * 256 + threadIdx.x;
  if (idx >= K * N) return;
  int k = idx / N, n = idx - k * N;
  float v = W[(size_t)(row0 + k) * N + n];
  unsigned short h = f2bh(v);
  hi[(size_t)n * K + k] = h;
  lo[(size_t)n * K + k] = f2bh(v - bh2f(h));
}

// ---------------------------------------------------------------- split-bf16 MFMA layer
// A (f32, LDS, [64][AS]) x W (K x N, prepped transposed hi/lo in global) -> acc (f32, no bias).
// Each wave owns rows [wv*16, wv*16+16). 3 MFMAs per tile: Ah*Wh + Al*Wh + Ah*Wl.
template<int K, int N, int AS, int WS, bool XYZC>
DEVINL void do_layer(const unsigned short* __restrict__ Ghi, const unsigned short* __restrict__ Glo,
                     const float* __restrict__ Wxyz,
                     const float* __restrict__ A, unsigned short* __restrict__ Whi,
                     unsigned short* __restrict__ Wlo, const float* __restrict__ sxyz,
                     f32x4* acc, int t) {
  constexpr int KT = K / 32;
  constexpr int NCH = N / 64;
  const int l = t & 63, wv = t >> 6;
  bf16x8 ahi[KT], alo[KT];
  {
    const int row = wv * 16 + (l & 15);
    const float* ap = A + row * AS + (l >> 4) * 8;
#pragma unroll
    for (int kt = 0; kt < KT; ++kt) {
      float4 v0 = *reinterpret_cast<const float4*>(ap + kt * 32);
      float4 v1 = *reinterpret_cast<const float4*>(ap + kt * 32 + 4);
      float f[8] = {v0.x, v0.y, v0.z, v0.w, v1.x, v1.y, v1.z, v1.w};
      bf16x8 h, lo2;
#pragma unroll
      for (int j = 0; j < 8; ++j) {
        unsigned short hb = f2bh(f[j]);
        h[j] = (short)hb;
        lo2[j] = (short)f2bh(f[j] - bh2f(hb));
      }
      ahi[kt] = h; alo[kt] = lo2;
    }
  }
#pragma unroll
  for (int i = 0; i < N / 16; ++i) acc[i] = f32x4{0.f, 0.f, 0.f, 0.f};

#pragma unroll
  for (int c = 0; c < NCH; ++c) {
    __syncthreads();  // all waves done reading previous Wt contents
    {
      constexpr int K8 = K / 8;
      for (int u = t; u < 64 * K8; u += 256) {
        int nn = u / K8, k8 = (u - nn * K8) * 8;
        *reinterpret_cast<u16x8*>(Whi + nn * WS + k8) =
            *reinterpret_cast<const u16x8*>(Ghi + (size_t)(c * 64 + nn) * K + k8);
        *reinterpret_cast<u16x8*>(Wlo + nn * WS + k8) =
            *reinterpret_cast<const u16x8*>(Glo + (size_t)(c * 64 + nn) * K + k8);
      }
    }
    __syncthreads();
#pragma unroll
    for (int ct = 0; ct < 4; ++ct) {
      const unsigned short* wp = Whi + (ct * 16 + (l & 15)) * WS + (l >> 4) * 8;
      const unsigned short* wq = Wlo + (ct * 16 + (l & 15)) * WS + (l >> 4) * 8;
      f32x4 a = acc[c * 4 + ct];
#pragma unroll
      for (int kt = 0; kt < KT; ++kt) {
        bf16x8 wh = *reinterpret_cast<const bf16x8*>(wp + kt * 32);
        bf16x8 wl = *reinterpret_cast<const bf16x8*>(wq + kt * 32);
        a = __builtin_amdgcn_mfma_f32_16x16x32_bf16(ahi[kt], wh, a, 0, 0, 0);
        a = __builtin_amdgcn_mfma_f32_16x16x32_bf16(alo[kt], wh, a, 0, 0, 0);
        a = __builtin_amdgcn_mfma_f32_16x16x32_bf16(ahi[kt], wl, a, 0, 0, 0);
      }
      acc[c * 4 + ct] = a;
    }
  }
  if constexpr (XYZC) {  // exact f32 correction for the 3 xyz input dims (W rows 0..2)
    float xr[4][3];
#pragma unroll
    for (int r = 0; r < 4; ++r) {
      int row = wv * 16 + (l >> 4) * 4 + r;
      xr[r][0] = sxyz[row * 4 + 0];
      xr[r][1] = sxyz[row * 4 + 1];
      xr[r][2] = sxyz[row * 4 + 2];
    }
#pragma unroll
    for (int gt = 0; gt < N / 16; ++gt) {
      int col = gt * 16 + (l & 15);
      float w0 = Wxyz[col], w1 = Wxyz[N + col], w2 = Wxyz[2 * N + col];
#pragma unroll
      for (int r = 0; r < 4; ++r)
        acc[gt][r] += xr[r][0] * w0 + xr[r][1] * w1 + xr[r][2] * w2;
    }
  }
}

// ---------------------------------------------------------------- fused SA stage (gather + 3 layers + maxpool)
template<int NPTS, int Q, int M, int GPB, int FD, int C1, int C2, int C3>
__global__ __launch_bounds__(256) void sa_mfma_kernel(
    const float* __restrict__ pts, const float* __restrict__ centers,
    const int* __restrict__ gidx, const float* __restrict__ feats,
    const float* __restrict__ W0, const float* __restrict__ B0,
    const unsigned short* __restrict__ G0h, const unsigned short* __restrict__ G0l,
    const unsigned short* __restrict__ G1h, const unsigned short* __restrict__ G1l,
    const float* __restrict__ B1,
    const unsigned short* __restrict__ G2h, const unsigned short* __restrict__ G2l,
    const float* __restrict__ B2,
    float* __restrict__ fout) {
  static_assert(M * GPB == 64, "");
  constexpr int MK1 = (FD > C1 ? FD : C1);
  constexpr int MAXK = (MK1 > C2 ? MK1 : C2);
  constexpr int AS = MAXK + 8;
  constexpr int WS = MAXK + 8;
  __shared__ __align__(16) float A[64 * AS];
  __shared__ __align__(16) unsigned short Whi[64 * WS];
  __shared__ __align__(16) unsigned short Wlo[64 * WS];
  __shared__ float sxyz[64 * 4];
  __shared__ int idxs[64];
  __shared__ float ctr[GPB][4];
  __shared__ float red[4][C3];

  const int t = threadIdx.x;
  const int blk = blockIdx.x;
  const int b = blk / (Q / GPB);
  const int q0 = (blk % (Q / GPB)) * GPB;
  const int l = t & 63, wv = t >> 6;

  if (t < GPB * 3) {
    int g = t / 3, c2 = t % 3;
    ctr[g][c2] = centers[((size_t)b * Q + q0 + g) * 3 + c2];
  }
  for (int m = t; m < 64; m += 256)
    idxs[m] = gidx[((size_t)b * Q + q0 + (m / M)) * M + (m % M)];
  __syncthreads();
  const float* pb = pts + (size_t)b * NPTS * 3;
  for (int m = t; m < 64; m += 256) {
    int g = m / M, i = idxs[m];
    sxyz[m * 4 + 0] = pb[i * 3 + 0] - ctr[g][0];
    sxyz[m * 4 + 1] = pb[i * 3 + 1] - ctr[g][1];
    sxyz[m * 4 + 2] = pb[i * 3 + 2] - ctr[g][2];
  }
  if constexpr (FD > 0) {
    const int m = t >> 2, co = (t & 3) * (FD / 4);
    const float* src = feats + ((size_t)b * NPTS + idxs[m]) * FD + co;
    float* dst = A + m * AS + co;
#pragma unroll
    for (int j = 0; j < FD / 4; j += 4)
      *reinterpret_cast<float4*>(dst + j) = *reinterpret_cast<const float4*>(src + j);
  }
  __syncthreads();

  f32x4 acc[C3 / 16];

  if constexpr (FD == 0) {
    // layer0: 3 -> C1 in exact f32 VALU (K=3 too small for MFMA)
    for (int u = t; u < 64 * C1; u += 256) {
      int m = u / C1, c2 = u - m * C1;
      float v = B0[c2] + sxyz[m * 4 + 0] * W0[0 * C1 + c2]
                       + sxyz[m * 4 + 1] * W0[1 * C1 + c2]
                       + sxyz[m * 4 + 2] * W0[2 * C1 + c2];
      A[m * AS + c2] = fmaxf(v, 0.f);
    }
    __syncthreads();
  } else {
    do_layer<FD, C1, AS, WS, true>(G0h, G0l, W0, A, Whi, Wlo, sxyz, acc, t);
#pragma unroll
    for (int gt = 0; gt < C1 / 16; ++gt) {
      int col = gt * 16 + (l & 15);
      float bia = B0[col];
#pragma unroll
      for (int r = 0; r < 4; ++r)
        A[(wv * 16 + (l >> 4) * 4 + r) * AS + col] = fmaxf(acc[gt][r] + bia, 0.f);
    }
  }

  do_layer<C1, C2, AS, WS, false>(G1h, G1l, nullptr, A, Whi, Wlo, sxyz, acc, t);
#pragma unroll
  for (int gt = 0; gt < C2 / 16; ++gt) {
    int col = gt * 16 + (l & 15);
    float bia = B1[col];
#pragma unroll
    for (int r = 0; r < 4; ++r)
      A[(wv * 16 + (l >> 4) * 4 + r) * AS + col] = fmaxf(acc[gt][r] + bia, 0.f);
  }

  do_layer<C2, C3, AS, WS, false>(G2h, G2l, nullptr, A, Whi, Wlo, sxyz, acc, t);
  // maxpool epilogue: max over rows within each group, then +bias, relu
#pragma unroll
  for (int gt = 0; gt < C3 / 16; ++gt) {
    int col = gt * 16 + (l & 15);
    float v = fmaxf(fmaxf(acc[gt][0], acc[gt][1]), fmaxf(acc[gt][2], acc[gt][3]));
    v = fmaxf(v, __shfl_xor(v, 16, 64));
    v = fmaxf(v, __shfl_xor(v, 32, 64));
    if (l < 16) red[wv][col] = v + B2[col];
  }
  __syncthreads();
  constexpr int WPG = 4 / GPB;
  for (int u = t; u < GPB * C3; u += 256) {
    int g = u / C3, c2 = u - g * C3;
    float v = red[g * WPG][c2];
#pragma unroll
    for (int w = 1; w < WPG; ++w) v = fmaxf(v, red[g * WPG + w][c2]);
    fout[((size_t)b * Q + q0 + g) * C3 + c2] = fmaxf(v, 0.f);
  }
}

// ---------------------------------------------------------------- SA3 (global MLP, f32)
template<int K, int CT, bool CONCAT, bool DOMAX>
__global__ __launch_bounds__(256) void sa3_kernel(
    const float* __restrict__ X, const float* __restrict__ X2,
    const float* __restrict__ W, const float* __restrict__ Bb,
    float* __restrict__ Out) {
  constexpr int M = 128, SP = 132, KC = 64;
  __shared__ float ldsA[KC * SP];
  __shared__ float red[32 * 64];
  const int t = threadIdx.x;
  const int b = blockIdx.x;
  const int c0b = blockIdx.y * 64;
  const int cg = t & 7, sg = t >> 3;
  const int m0 = sg * 4;
  const int c0 = c0b + cg * 8;
  float acc[4][8];
#pragma unroll
  for (int j = 0; j < 8; ++j) {
    float v = Bb[c0 + j];
    acc[0][j] = v; acc[1][j] = v; acc[2][j] = v; acc[3][j] = v;
  }
  for (int kc = 0; kc < K; kc += KC) {
    const int kn = (K - kc < KC) ? (K - kc) : KC;
    __syncthreads();
    for (int u = t; u < M * KC; u += 256) {
      int m = u >> 6, kk = u & 63;
      if (kk < kn) {
        int k = kc + kk;
        float v;
        if constexpr (CONCAT) {
          v = (k < 3) ? X[((size_t)b * M + m) * 3 + k]
                      : X2[((size_t)b * M + m) * 256 + (k - 3)];
        } else {
          v = X[((size_t)b * M + m) * K + k];
        }
        ldsA[kk * SP + m] = v;
      }
    }
    __syncthreads();
    for (int kk = 0; kk < kn; ++kk) {
      const float4 a = *reinterpret_cast<const float4*>(ldsA + kk * SP + m0);
      const float* wr = W + (size_t)(kc + kk) * CT + c0;
#pragma unroll
      for (int j = 0; j < 8; ++j) {
        float w = wr[j];
        acc[0][j] += a.x * w; acc[1][j] += a.y * w;
        acc[2][j] += a.z * w; acc[3][j] += a.w * w;
      }
    }
  }
  if constexpr (!DOMAX) {
#pragma unroll
    for (int i = 0; i < 4; ++i) {
      float* o = Out + ((size_t)b * M + m0 + i) * CT + c0;
#pragma unroll
      for (int j = 0; j < 8; ++j) o[j] = fmaxf(acc[i][j], 0.f);
    }
  } else {
#pragma unroll
    for (int j = 0; j < 8; ++j) {
      float mv = fmaxf(fmaxf(fmaxf(acc[0][j], acc[1][j]), fmaxf(acc[2][j], acc[3][j])), 0.f);
      red[sg * 64 + cg * 8 + j] = mv;
    }
    __syncthreads();
    for (int c = t; c < 64; c += 256) {
      float mv = red[c];
#pragma unroll
      for (int r = 1; r < 32; ++r) mv = fmaxf(mv, red[r * 64 + c]);
      Out[(size_t)b * CT + c0b + c] = mv;
    }
  }
}

// ---------------------------------------------------------------- heads
__global__ __launch_bounds__(256) void heads_kernel(const float* __restrict__ feat,
                                                    const float* __restrict__ cw,
                                                    const float* __restrict__ cb,
                                                    const float* __restrict__ rw,
                                                    const float* __restrict__ rb,
                                                    float* __restrict__ out) {
  const int b = blockIdx.x, t = threadIdx.x;
  const float* fb = feat + (size_t)b * 1024;
  float a0 = 0, a1 = 0, a2 = 0, a3 = 0, a4 = 0;
  for (int k = t; k < 1024; k += 256) {
    float f = fb[k];
    a0 += f * cw[k];
    const float* r = rw + (size_t)k * 4;
    a1 += f * r[0]; a2 += f * r[1]; a3 += f * r[2]; a4 += f * r[3];
  }
#pragma unroll
  for (int m = 32; m >= 1; m >>= 1) {
    a0 += __shfl_xor(a0, m, 64); a1 += __shfl_xor(a1, m, 64);
    a2 += __shfl_xor(a2, m, 64); a3 += __shfl_xor(a3, m, 64);
    a4 += __shfl_xor(a4, m, 64);
  }
  __shared__ float red[4][5];
  const int wv = t >> 6, ln = t & 63;
  if (ln == 0) { red[wv][0] = a0; red[wv][1] = a1; red[wv][2] = a2; red[wv][3] = a3; red[wv][4] = a4; }
  __syncthreads();
  if (t == 0) {
    float s0 = red[0][0] + red[1][0] + red[2][0] + red[3][0];
    float s1 = red[0][1] + red[1][1] + red[2][1] + red[3][1];
    float s2 = red[0][2] + red[1][2] + red[2][2] + red[3][2];
    float s3 = red[0][3] + red[1][3] + red[2][3] + red[3][3];
    float s4 = red[0][4] + red[1][4] + red[2][4] + red[3][4];
    out[b] = s0 + cb[0];
    out[32 + b * 4 + 0] = s1 + rb[0];
    out[32 + b * 4 + 1] = s2 + rb[1];
    out[32 + b * 4 + 2] = s3 + rb[2];
    out[32 + b * 4 + 3] = s4 + rb[3];
  }
}

// ---------------------------------------------------------------- launch
extern "C" void kernel_launch(void* const* d_in, const int* in_sizes, int n_in,
                              void* d_out, int out_size, void* d_ws, size_t ws_size,
                              hipStream_t stream) {
  (void)in_sizes; (void)n_in; (void)out_size; (void)ws_size;
  const float* xyz  = (const float*)d_in[0];
  const float* s1w0 = (const float*)d_in[1];  const float* s1b0 = (const float*)d_in[2];
  const float* s1w1 = (const float*)d_in[3];  const float* s1b1 = (const float*)d_in[4];
  const float* s1w2 = (const float*)d_in[5];  const float* s1b2 = (const float*)d_in[6];
  const float* s2w0 = (const float*)d_in[7];  const float* s2b0 = (const float*)d_in[8];
  const float* s2w1 = (const float*)d_in[9];  const float* s2b1 = (const float*)d_in[10];
  const float* s2w2 = (const float*)d_in[11]; const float* s2b2 = (const float*)d_in[12];
  const float* s3w0 = (const float*)d_in[13]; const float* s3b0 = (const float*)d_in[14];
  const float* s3w1 = (const float*)d_in[15]; const float* s3b1 = (const float*)d_in[16];
  const float* s3w2 = (const float*)d_in[17]; const float* s3b2 = (const float*)d_in[18];
  const float* clsw = (const float*)d_in[19]; const float* clsb = (const float*)d_in[20];
  const float* regw = (const float*)d_in[21]; const float* regb = (const float*)d_in[22];

  char* ws = (char*)d_ws;
  float* nx1   = (float*)(ws + 0);          // 32*512*3
  int*   gidx1 = (int*)  (ws + 196608);     // 32*512*32
  float* f1    = (float*)(ws + 2293760);    // 32*512*128
  float* nx2   = (float*)(ws + 10682368);   // 32*128*3
  int*   gidx2 = (int*)  (ws + 10731520);   // 32*128*64
  float* f2    = (float*)(ws + 11780096);   // 32*128*256
  float* h1    = (float*)(ws + 15974400);   // 32*128*256
  float* h2    = (float*)(ws + 20168704);   // 32*128*512
  float* feat  = (float*)(ws + 28557312);   // 32*1024

  // Prepped hi/lo transposed weights live in the h2 region: written by wprep at
  // the start, consumed by sa_mfma (SA1/SA2), then legitimately overwritten by
  // sa3's h2 output afterwards. Deterministic: rewritten every call.
  unsigned short* wt = (unsigned short*)(ws + 20168704);
  unsigned short* g11h = wt;            // 64*64
  unsigned short* g11l = wt + 4096;
  unsigned short* g12h = wt + 8192;     // 128*64
  unsigned short* g12l = wt + 16384;
  unsigned short* g20h = wt + 24576;    // 128*128 (rows 3..130 of s2w0)
  unsigned short* g20l = wt + 40960;
  unsigned short* g21h = wt + 57344;    // 128*128
  unsigned short* g21l = wt + 73728;
  unsigned short* g22h = wt + 90112;    // 256*128
  unsigned short* g22l = wt + 122880;   // ends at 155648 shorts = 311296 B < 8 MB

  const float r21 = (float)(0.2 * 0.2);
  const float r22 = (float)(0.4 * 0.4);

  wprep_kernel<<<16, 256, 0, stream>>>(s1w1, 64, 64, 0, g11h, g11l);
  wprep_kernel<<<32, 256, 0, stream>>>(s1w2, 64, 128, 0, g12h, g12l);
  wprep_kernel<<<64, 256, 0, stream>>>(s2w0, 128, 128, 3, g20h, g20l);
  wprep_kernel<<<64, 256, 0, stream>>>(s2w1, 128, 128, 0, g21h, g21l);
  wprep_kernel<<<128, 256, 0, stream>>>(s2w2, 128, 256, 0, g22h, g22l);

  fps_kernel<4096, 512, 256><<<32, 256, 0, stream>>>(xyz, nx1);
  bq_kernel<4096, 32><<<4096, 256, 0, stream>>>(xyz, nx1, gidx1, 512, r21);
  sa_mfma_kernel<4096, 512, 32, 2, 0, 64, 64, 128><<<8192, 256, 0, stream>>>(
      xyz, nx1, gidx1, (const float*)nullptr, s1w0, s1b0,
      nullptr, nullptr, g11h, g11l, s1b1, g12h, g12l, s1b2, f1);
  fps_kernel<512, 128, 64><<<32, 64, 0, stream>>>(nx1, nx2);
  bq_kernel<512, 64><<<1024, 256, 0, stream>>>(nx1, nx2, gidx2, 128, r22);
  sa_mfma_kernel<512, 128, 64, 1, 128, 128, 128, 256><<<4096, 256, 0, stream>>>(
      nx1, nx2, gidx2, f1, s2w0, s2b0,
      g20h, g20l, g21h, g21l, s2b1, g22h, g22l, s2b2, f2);
  sa3_kernel<259, 256, true, false><<<dim3(32, 4), 256, 0, stream>>>(nx2, f2, s3w0, s3b0, h1);
  sa3_kernel<256, 512, false, false><<<dim3(32, 8), 256, 0, stream>>>(h1, nullptr, s3w1, s3b1, h2);
  sa3_kernel<512, 1024, false, true><<<dim3(32, 16), 256, 0, stream>>>(h2, nullptr, s3w2, s3b2, feat);
  heads_kernel<<<32, 256, 0, stream>>>(feat, clsw, clsb, regw, regb, (float*)d_out);
}

// Round 4
// 811.329 us; speedup vs baseline: 2.2615x; 1.3971x over previous
//
#include <hip/hip_runtime.h>

#define DEVINL __device__ __forceinline__

typedef __attribute__((ext_vector_type(8))) short bf16x8;
typedef __attribute__((ext_vector_type(8))) unsigned short u16x8;
typedef __attribute__((ext_vector_type(4))) float f32x4;

// RNE f32 -> bf16 bits (no NaN handling needed for this workload)
DEVINL unsigned short f2bh(float f){
  unsigned u = __float_as_uint(f);
  return (unsigned short)((u + 0x7FFFu + ((u >> 16) & 1u)) >> 16);
}
DEVINL float bh2f(unsigned short h){ return __uint_as_float(((unsigned)h) << 16); }

// Wave64 max-reduce of a u64 key via DPP (VALU latency, no DS pipe).
// row_shr 1/2/4/8 accumulate toward lane 15 of each 16-row; bcast15/31
// propagate upward; lane 63 ends with the wave max. bound_ctrl=1 injects 0
// for invalid source lanes (identity: keys are always > 0 here).
DEVINL unsigned long long dpp_max_u64(unsigned long long k) {
#define DPP_STEP(ctrl)                                                        \
  {                                                                           \
    int hi = (int)(k >> 32), lo = (int)(unsigned)k;                           \
    int oh = __builtin_amdgcn_update_dpp(0, hi, ctrl, 0xF, 0xF, 1);           \
    int ol = __builtin_amdgcn_update_dpp(0, lo, ctrl, 0xF, 0xF, 1);           \
    unsigned long long ok =                                                   \
        ((unsigned long long)(unsigned)oh << 32) | (unsigned)ol;              \
    if (ok > k) k = ok;                                                       \
  }
  DPP_STEP(0x111)  // row_shr:1
  DPP_STEP(0x112)  // row_shr:2
  DPP_STEP(0x114)  // row_shr:4
  DPP_STEP(0x118)  // row_shr:8
  DPP_STEP(0x142)  // row_bcast:15
  DPP_STEP(0x143)  // row_bcast:31
#undef DPP_STEP
  return k;
}

// ---------------------------------------------------------------- FPS
// Latency-optimized: no global stores in the loop (far indices recorded to
// LDS, centroids written once at the end), DPP-based wave argmax, one
// barrier per step (double-buffered u64 wave candidates). NT=64 has no
// barrier and no LDS exchange at all. Distance arithmetic and tie-break
// bit-identical to the verified r1 version.
template<int N, int NP, int NT>
__global__ __launch_bounds__(NT) void fps_kernel(const float* __restrict__ xyz,
                                                 float* __restrict__ nxyz) {
  constexpr int PTS = N / NT;
  constexpr int NW = NT / 64;
  const int b = blockIdx.x, t = threadIdx.x;
  __shared__ float xs[N], ys[N], zs[N];
  __shared__ int farr[NP];
  __shared__ unsigned long long sk[2][(NW > 1 ? NW : 1)];
  float px[PTS], py[PTS], pz[PTS], dst[PTS];
  const float* base = xyz + (size_t)b * N * 3;
#pragma unroll
  for (int j = 0; j < PTS; ++j) {
    int i = t + j * NT;
    float x = base[i * 3 + 0], y = base[i * 3 + 1], z = base[i * 3 + 2];
    px[j] = x; py[j] = y; pz[j] = z;
    xs[i] = x; ys[i] = y; zs[i] = z;
    dst[j] = 1e10f;
  }
  __syncthreads();
  int far = 0;
  const int wv = t >> 6, ln = t & 63;
  for (int s = 0; s < NP; ++s) {
    float cx = xs[far], cy = ys[far], cz = zs[far];
    if (t == 0) farr[s] = far;
    float bv = -1.f; int bi = 0;
#pragma unroll
    for (int j = 0; j < PTS; ++j) {
      // no-fma, left-to-right: matches numpy elementwise + sum order
      float dx = __fsub_rn(px[j], cx), dy = __fsub_rn(py[j], cy), dz = __fsub_rn(pz[j], cz);
      float d = __fadd_rn(__fadd_rn(__fmul_rn(dx, dx), __fmul_rn(dy, dy)), __fmul_rn(dz, dz));
      float nd = fminf(dst[j], d);
      dst[j] = nd;
      int i = t + j * NT;
      if (nd > bv) { bv = nd; bi = i; }  // strict >: first max kept per thread
    }
    // pack: max key == max dist, tie -> larger ~idx == smaller idx
    unsigned long long key =
        ((unsigned long long)__float_as_uint(bv) << 32) | (unsigned)(~bi);
    key = dpp_max_u64(key);
    if constexpr (NW == 1) {
      int rl = __builtin_amdgcn_readlane((int)(unsigned)key, 63);
      far = (int)(~(unsigned)rl);
    } else {
      const int p = s & 1;
      if (ln == 63) sk[p][wv] = key;
      __syncthreads();
      unsigned long long m = sk[p][0];
#pragma unroll
      for (int q = 1; q < NW; ++q) {
        unsigned long long qk = sk[p][q];
        if (qk > m) m = qk;
      }
      far = (int)(~(unsigned)m);
    }
  }
  __syncthreads();
  for (int s2 = t; s2 < NP; s2 += NT) {
    int fi = farr[s2];
    float* o = nxyz + ((size_t)b * NP + s2) * 3;
    o[0] = xs[fi]; o[1] = ys[fi]; o[2] = zs[fi];
  }
}

// ---------------------------------------------------------------- ball query (unchanged)
template<int N, int NS>
__global__ __launch_bounds__(256) void bq_kernel(const float* __restrict__ pts,
                                                 const float* __restrict__ centers,
                                                 int* __restrict__ gidx, int Q, float r2) {
  const int wv = threadIdx.x >> 6, ln = threadIdx.x & 63;
  const int g = blockIdx.x * 4 + wv;
  const int b = g / Q, q = g % Q;
  const float* pb = pts + (size_t)b * N * 3;
  const float* c = centers + ((size_t)b * Q + q) * 3;
  const float cx = c[0], cy = c[1], cz = c[2];
  __shared__ int gbuf[4][NS];
  int taken = 0;
  for (int base = 0; base < N; base += 64) {
    if (taken >= NS) break;
    int i = base + ln;
    float dx = __fsub_rn(pb[i * 3 + 0], cx), dy = __fsub_rn(pb[i * 3 + 1], cy),
          dz = __fsub_rn(pb[i * 3 + 2], cz);
    float d = __fadd_rn(__fadd_rn(__fmul_rn(dx, dx), __fmul_rn(dy, dy)), __fmul_rn(dz, dz));
    bool in = (d <= r2);
    unsigned long long mk = __ballot(in);
    int rank = __popcll(mk & ((1ull << ln) - 1ull));
    int pos = taken + rank;
    if (in && pos < NS) gbuf[wv][pos] = i;
    taken += (int)__popcll(mk);
  }
  int total = taken < NS ? taken : NS;
  int first = gbuf[wv][0];
  int* out = gidx + ((size_t)b * Q + q) * NS;
  for (int j = ln; j < NS; j += 64) out[j] = (j < total) ? gbuf[wv][j] : first;
}

// ---------------------------------------------------------------- weight prep: transpose + hi/lo split
__global__ __launch_bounds__(256) void wprep_kernel(const float* __restrict__ W, int K, int N,
                                                    int row0, unsigned short* __restrict__ hi,
                                                    unsigned short* __restrict__ lo) {
  int idx = blockIdx.x * 256 + threadIdx.x;
  if (idx >= K * N) return;
  int k = idx / N, n = idx - k * N;
  float v = W[(size_t)(row0 + k) * N + n];
  unsigned short h = f2bh(v);
  hi[(size_t)n * K + k] = h;
  lo[(size_t)n * K + k] = f2bh(v - bh2f(h));
}

// ---------------------------------------------------------------- split-bf16 MFMA layer
// A (f32, LDS, [64][AS]) x W (K x N, prepped transposed hi/lo in global) -> acc (f32, no bias).
// Each wave owns rows [wv*16, wv*16+16). 3 MFMAs per tile: Ah*Wh + Al*Wh + Ah*Wl.
template<int K, int N, int AS, int WS, bool XYZC>
DEVINL void do_layer(const unsigned short* __restrict__ Ghi, const unsigned short* __restrict__ Glo,
                     const float* __restrict__ Wxyz,
                     const float* __restrict__ A, unsigned short* __restrict__ Whi,
                     unsigned short* __restrict__ Wlo, const float* __restrict__ sxyz,
                     f32x4* acc, int t) {
  constexpr int KT = K / 32;
  constexpr int NCH = N / 64;
  const int l = t & 63, wv = t >> 6;
  bf16x8 ahi[KT], alo[KT];
  {
    const int row = wv * 16 + (l & 15);
    const float* ap = A + row * AS + (l >> 4) * 8;
#pragma unroll
    for (int kt = 0; kt < KT; ++kt) {
      float4 v0 = *reinterpret_cast<const float4*>(ap + kt * 32);
      float4 v1 = *reinterpret_cast<const float4*>(ap + kt * 32 + 4);
      float f[8] = {v0.x, v0.y, v0.z, v0.w, v1.x, v1.y, v1.z, v1.w};
      bf16x8 h, lo2;
#pragma unroll
      for (int j = 0; j < 8; ++j) {
        unsigned short hb = f2bh(f[j]);
        h[j] = (short)hb;
        lo2[j] = (short)f2bh(f[j] - bh2f(hb));
      }
      ahi[kt] = h; alo[kt] = lo2;
    }
  }
#pragma unroll
  for (int i = 0; i < N / 16; ++i) acc[i] = f32x4{0.f, 0.f, 0.f, 0.f};

#pragma unroll
  for (int c = 0; c < NCH; ++c) {
    __syncthreads();  // all waves done reading previous Wt contents
    {
      constexpr int K8 = K / 8;
      for (int u = t; u < 64 * K8; u += 256) {
        int nn = u / K8, k8 = (u - nn * K8) * 8;
        *reinterpret_cast<u16x8*>(Whi + nn * WS + k8) =
            *reinterpret_cast<const u16x8*>(Ghi + (size_t)(c * 64 + nn) * K + k8);
        *reinterpret_cast<u16x8*>(Wlo + nn * WS + k8) =
            *reinterpret_cast<const u16x8*>(Glo + (size_t)(c * 64 + nn) * K + k8);
      }
    }
    __syncthreads();
#pragma unroll
    for (int ct = 0; ct < 4; ++ct) {
      const unsigned short* wp = Whi + (ct * 16 + (l & 15)) * WS + (l >> 4) * 8;
      const unsigned short* wq = Wlo + (ct * 16 + (l & 15)) * WS + (l >> 4) * 8;
      f32x4 a = acc[c * 4 + ct];
#pragma unroll
      for (int kt = 0; kt < KT; ++kt) {
        bf16x8 wh = *reinterpret_cast<const bf16x8*>(wp + kt * 32);
        bf16x8 wl = *reinterpret_cast<const bf16x8*>(wq + kt * 32);
        a = __builtin_amdgcn_mfma_f32_16x16x32_bf16(ahi[kt], wh, a, 0, 0, 0);
        a = __builtin_amdgcn_mfma_f32_16x16x32_bf16(alo[kt], wh, a, 0, 0, 0);
        a = __builtin_amdgcn_mfma_f32_16x16x32_bf16(ahi[kt], wl, a, 0, 0, 0);
      }
      acc[c * 4 + ct] = a;
    }
  }
  if constexpr (XYZC) {  // exact f32 correction for the 3 xyz input dims (W rows 0..2)
    float xr[4][3];
#pragma unroll
    for (int r = 0; r < 4; ++r) {
      int row = wv * 16 + (l >> 4) * 4 + r;
      xr[r][0] = sxyz[row * 4 + 0];
      xr[r][1] = sxyz[row * 4 + 1];
      xr[r][2] = sxyz[row * 4 + 2];
    }
#pragma unroll
    for (int gt = 0; gt < N / 16; ++gt) {
      int col = gt * 16 + (l & 15);
      float w0 = Wxyz[col], w1 = Wxyz[N + col], w2 = Wxyz[2 * N + col];
#pragma unroll
      for (int r = 0; r < 4; ++r)
        acc[gt][r] += xr[r][0] * w0 + xr[r][1] * w1 + xr[r][2] * w2;
    }
  }
}

// ---------------------------------------------------------------- fused SA stage (gather + 3 layers + maxpool)
template<int NPTS, int Q, int M, int GPB, int FD, int C1, int C2, int C3>
__global__ __launch_bounds__(256) void sa_mfma_kernel(
    const float* __restrict__ pts, const float* __restrict__ centers,
    const int* __restrict__ gidx, const float* __restrict__ feats,
    const float* __restrict__ W0, const float* __restrict__ B0,
    const unsigned short* __restrict__ G0h, const unsigned short* __restrict__ G0l,
    const unsigned short* __restrict__ G1h, const unsigned short* __restrict__ G1l,
    const float* __restrict__ B1,
    const unsigned short* __restrict__ G2h, const unsigned short* __restrict__ G2l,
    const float* __restrict__ B2,
    float* __restrict__ fout) {
  static_assert(M * GPB == 64, "");
  constexpr int MK1 = (FD > C1 ? FD : C1);
  constexpr int MAXK = (MK1 > C2 ? MK1 : C2);
  constexpr int AS = MAXK + 8;
  constexpr int WS = MAXK + 8;
  __shared__ __align__(16) float A[64 * AS];
  __shared__ __align__(16) unsigned short Whi[64 * WS];
  __shared__ __align__(16) unsigned short Wlo[64 * WS];
  __shared__ float sxyz[64 * 4];
  __shared__ int idxs[64];
  __shared__ float ctr[GPB][4];
  __shared__ float red[4][C3];

  const int t = threadIdx.x;
  const int blk = blockIdx.x;
  const int b = blk / (Q / GPB);
  const int q0 = (blk % (Q / GPB)) * GPB;
  const int l = t & 63, wv = t >> 6;

  if (t < GPB * 3) {
    int g = t / 3, c2 = t % 3;
    ctr[g][c2] = centers[((size_t)b * Q + q0 + g) * 3 + c2];
  }
  for (int m = t; m < 64; m += 256)
    idxs[m] = gidx[((size_t)b * Q + q0 + (m / M)) * M + (m % M)];
  __syncthreads();
  const float* pb = pts + (size_t)b * NPTS * 3;
  for (int m = t; m < 64; m += 256) {
    int g = m / M, i = idxs[m];
    sxyz[m * 4 + 0] = pb[i * 3 + 0] - ctr[g][0];
    sxyz[m * 4 + 1] = pb[i * 3 + 1] - ctr[g][1];
    sxyz[m * 4 + 2] = pb[i * 3 + 2] - ctr[g][2];
  }
  if constexpr (FD > 0) {
    const int m = t >> 2, co = (t & 3) * (FD / 4);
    const float* src = feats + ((size_t)b * NPTS + idxs[m]) * FD + co;
    float* dst = A + m * AS + co;
#pragma unroll
    for (int j = 0; j < FD / 4; j += 4)
      *reinterpret_cast<float4*>(dst + j) = *reinterpret_cast<const float4*>(src + j);
  }
  __syncthreads();

  f32x4 acc[C3 / 16];

  if constexpr (FD == 0) {
    // layer0: 3 -> C1 in exact f32 VALU (K=3 too small for MFMA)
    for (int u = t; u < 64 * C1; u += 256) {
      int m = u / C1, c2 = u - m * C1;
      float v = B0[c2] + sxyz[m * 4 + 0] * W0[0 * C1 + c2]
                       + sxyz[m * 4 + 1] * W0[1 * C1 + c2]
                       + sxyz[m * 4 + 2] * W0[2 * C1 + c2];
      A[m * AS + c2] = fmaxf(v, 0.f);
    }
    __syncthreads();
  } else {
    do_layer<FD, C1, AS, WS, true>(G0h, G0l, W0, A, Whi, Wlo, sxyz, acc, t);
#pragma unroll
    for (int gt = 0; gt < C1 / 16; ++gt) {
      int col = gt * 16 + (l & 15);
      float bia = B0[col];
#pragma unroll
      for (int r = 0; r < 4; ++r)
        A[(wv * 16 + (l >> 4) * 4 + r) * AS + col] = fmaxf(acc[gt][r] + bia, 0.f);
    }
  }

  do_layer<C1, C2, AS, WS, false>(G1h, G1l, nullptr, A, Whi, Wlo, sxyz, acc, t);
#pragma unroll
  for (int gt = 0; gt < C2 / 16; ++gt) {
    int col = gt * 16 + (l & 15);
    float bia = B1[col];
#pragma unroll
    for (int r = 0; r < 4; ++r)
      A[(wv * 16 + (l >> 4) * 4 + r) * AS + col] = fmaxf(acc[gt][r] + bia, 0.f);
  }

  do_layer<C2, C3, AS, WS, false>(G2h, G2l, nullptr, A, Whi, Wlo, sxyz, acc, t);
  // maxpool epilogue: max over rows within each group, then +bias, relu
#pragma unroll
  for (int gt = 0; gt < C3 / 16; ++gt) {
    int col = gt * 16 + (l & 15);
    float v = fmaxf(fmaxf(acc[gt][0], acc[gt][1]), fmaxf(acc[gt][2], acc[gt][3]));
    v = fmaxf(v, __shfl_xor(v, 16, 64));
    v = fmaxf(v, __shfl_xor(v, 32, 64));
    if (l < 16) red[wv][col] = v + B2[col];
  }
  __syncthreads();
  constexpr int WPG = 4 / GPB;
  for (int u = t; u < GPB * C3; u += 256) {
    int g = u / C3, c2 = u - g * C3;
    float v = red[g * WPG][c2];
#pragma unroll
    for (int w = 1; w < WPG; ++w) v = fmaxf(v, red[g * WPG + w][c2]);
    fout[((size_t)b * Q + q0 + g) * C3 + c2] = fmaxf(v, 0.f);
  }
}

// ---------------------------------------------------------------- SA3 (global MLP, f32)
template<int K, int CT, bool CONCAT, bool DOMAX>
__global__ __launch_bounds__(256) void sa3_kernel(
    const float* __restrict__ X, const float* __restrict__ X2,
    const float* __restrict__ W, const float* __restrict__ Bb,
    float* __restrict__ Out) {
  constexpr int M = 128, SP = 132, KC = 64;
  __shared__ float ldsA[KC * SP];
  __shared__ float red[32 * 64];
  const int t = threadIdx.x;
  const int b = blockIdx.x;
  const int c0b = blockIdx.y * 64;
  const int cg = t & 7, sg = t >> 3;
  const int m0 = sg * 4;
  const int c0 = c0b + cg * 8;
  float acc[4][8];
#pragma unroll
  for (int j = 0; j < 8; ++j) {
    float v = Bb[c0 + j];
    acc[0][j] = v; acc[1][j] = v; acc[2][j] = v; acc[3][j] = v;
  }
  for (int kc = 0; kc < K; kc += KC) {
    const int kn = (K - kc < KC) ? (K - kc) : KC;
    __syncthreads();
    for (int u = t; u < M * KC; u += 256) {
      int m = u >> 6, kk = u & 63;
      if (kk < kn) {
        int k = kc + kk;
        float v;
        if constexpr (CONCAT) {
          v = (k < 3) ? X[((size_t)b * M + m) * 3 + k]
                      : X2[((size_t)b * M + m) * 256 + (k - 3)];
        } else {
          v = X[((size_t)b * M + m) * K + k];
        }
        ldsA[kk * SP + m] = v;
      }
    }
    __syncthreads();
    for (int kk = 0; kk < kn; ++kk) {
      const float4 a = *reinterpret_cast<const float4*>(ldsA + kk * SP + m0);
      const float* wr = W + (size_t)(kc + kk) * CT + c0;
#pragma unroll
      for (int j = 0; j < 8; ++j) {
        float w = wr[j];
        acc[0][j] += a.x * w; acc[1][j] += a.y * w;
        acc[2][j] += a.z * w; acc[3][j] += a.w * w;
      }
    }
  }
  if constexpr (!DOMAX) {
#pragma unroll
    for (int i = 0; i < 4; ++i) {
      float* o = Out + ((size_t)b * M + m0 + i) * CT + c0;
#pragma unroll
      for (int j = 0; j < 8; ++j) o[j] = fmaxf(acc[i][j], 0.f);
    }
  } else {
#pragma unroll
    for (int j = 0; j < 8; ++j) {
      float mv = fmaxf(fmaxf(fmaxf(acc[0][j], acc[1][j]), fmaxf(acc[2][j], acc[3][j])), 0.f);
      red[sg * 64 + cg * 8 + j] = mv;
    }
    __syncthreads();
    for (int c = t; c < 64; c += 256) {
      float mv = red[c];
#pragma unroll
      for (int r = 1; r < 32; ++r) mv = fmaxf(mv, red[r * 64 + c]);
      Out[(size_t)b * CT + c0b + c] = mv;
    }
  }
}

// ---------------------------------------------------------------- heads
__global__ __launch_bounds__(256) void heads_kernel(const float* __restrict__ feat,
                                                    const float* __restrict__ cw,
                                                    const float* __restrict__ cb,
                                                    const float* __restrict__ rw,
                                                    const float* __restrict__ rb,
                                                    float* __restrict__ out) {
  const int b = blockIdx.x, t = threadIdx.x;
  const float* fb = feat + (size_t)b * 1024;
  float a0 = 0, a1 = 0, a2 = 0, a3 = 0, a4 = 0;
  for (int k = t; k < 1024; k += 256) {
    float f = fb[k];
    a0 += f * cw[k];
    const float* r = rw + (size_t)k * 4;
    a1 += f * r[0]; a2 += f * r[1]; a3 += f * r[2]; a4 += f * r[3];
  }
#pragma unroll
  for (int m = 32; m >= 1; m >>= 1) {
    a0 += __shfl_xor(a0, m, 64); a1 += __shfl_xor(a1, m, 64);
    a2 += __shfl_xor(a2, m, 64); a3 += __shfl_xor(a3, m, 64);
    a4 += __shfl_xor(a4, m, 64);
  }
  __shared__ float red[4][5];
  const int wv = t >> 6, ln = t & 63;
  if (ln == 0) { red[wv][0] = a0; red[wv][1] = a1; red[wv][2] = a2; red[wv][3] = a3; red[wv][4] = a4; }
  __syncthreads();
  if (t == 0) {
    float s0 = red[0][0] + red[1][0] + red[2][0] + red[3][0];
    float s1 = red[0][1] + red[1][1] + red[2][1] + red[3][1];
    float s2 = red[0][2] + red[1][2] + red[2][2] + red[3][2];
    float s3 = red[0][3] + red[1][3] + red[2][3] + red[3][3];
    float s4 = red[0][4] + red[1][4] + red[2][4] + red[3][4];
    out[b] = s0 + cb[0];
    out[32 + b * 4 + 0] = s1 + rb[0];
    out[32 + b * 4 + 1] = s2 + rb[1];
    out[32 + b * 4 + 2] = s3 + rb[2];
    out[32 + b * 4 + 3] = s4 + rb[3];
  }
}

// ---------------------------------------------------------------- launch
extern "C" void kernel_launch(void* const* d_in, const int* in_sizes, int n_in,
                              void* d_out, int out_size, void* d_ws, size_t ws_size,
                              hipStream_t stream) {
  (void)in_sizes; (void)n_in; (void)out_size; (void)ws_size;
  const float* xyz  = (const float*)d_in[0];
  const float* s1w0 = (const float*)d_in[1];  const float* s1b0 = (const float*)d_in[2];
  const float* s1w1 = (const float*)d_in[3];  const float* s1b1 = (const float*)d_in[4];
  const float* s1w2 = (const float*)d_in[5];  const float* s1b2 = (const float*)d_in[6];
  const float* s2w0 = (const float*)d_in[7];  const float* s2b0 = (const float*)d_in[8];
  const float* s2w1 = (const float*)d_in[9];  const float* s2b1 = (const float*)d_in[10];
  const float* s2w2 = (const float*)d_in[11]; const float* s2b2 = (const float*)d_in[12];
  const float* s3w0 = (const float*)d_in[13]; const float* s3b0 = (const float*)d_in[14];
  const float* s3w1 = (const float*)d_in[15]; const float* s3b1 = (const float*)d_in[16];
  const float* s3w2 = (const float*)d_in[17]; const float* s3b2 = (const float*)d_in[18];
  const float* clsw = (const float*)d_in[19]; const float* clsb = (const float*)d_in[20];
  const float* regw = (const float*)d_in[21]; const float* regb = (const float*)d_in[22];

  char* ws = (char*)d_ws;
  float* nx1   = (float*)(ws + 0);          // 32*512*3
  int*   gidx1 = (int*)  (ws + 196608);     // 32*512*32
  float* f1    = (float*)(ws + 2293760);    // 32*512*128
  float* nx2   = (float*)(ws + 10682368);   // 32*128*3
  int*   gidx2 = (int*)  (ws + 10731520);   // 32*128*64
  float* f2    = (float*)(ws + 11780096);   // 32*128*256
  float* h1    = (float*)(ws + 15974400);   // 32*128*256
  float* h2    = (float*)(ws + 20168704);   // 32*128*512
  float* feat  = (float*)(ws + 28557312);   // 32*1024

  // Prepped hi/lo transposed weights live in the h2 region: written by wprep at
  // the start, consumed by sa_mfma (SA1/SA2), then legitimately overwritten by
  // sa3's h2 output afterwards. Deterministic: rewritten every call.
  unsigned short* wt = (unsigned short*)(ws + 20168704);
  unsigned short* g11h = wt;            // 64*64
  unsigned short* g11l = wt + 4096;
  unsigned short* g12h = wt + 8192;     // 128*64
  unsigned short* g12l = wt + 16384;
  unsigned short* g20h = wt + 24576;    // 128*128 (rows 3..130 of s2w0)
  unsigned short* g20l = wt + 40960;
  unsigned short* g21h = wt + 57344;    // 128*128
  unsigned short* g21l = wt + 73728;
  unsigned short* g22h = wt + 90112;    // 256*128
  unsigned short* g22l = wt + 122880;   // ends at 155648 shorts = 311296 B < 8 MB

  const float r21 = (float)(0.2 * 0.2);
  const float r22 = (float)(0.4 * 0.4);

  wprep_kernel<<<16, 256, 0, stream>>>(s1w1, 64, 64, 0, g11h, g11l);
  wprep_kernel<<<32, 256, 0, stream>>>(s1w2, 64, 128, 0, g12h, g12l);
  wprep_kernel<<<64, 256, 0, stream>>>(s2w0, 128, 128, 3, g20h, g20l);
  wprep_kernel<<<64, 256, 0, stream>>>(s2w1, 128, 128, 0, g21h, g21l);
  wprep_kernel<<<128, 256, 0, stream>>>(s2w2, 128, 256, 0, g22h, g22l);

  fps_kernel<4096, 512, 256><<<32, 256, 0, stream>>>(xyz, nx1);
  bq_kernel<4096, 32><<<4096, 256, 0, stream>>>(xyz, nx1, gidx1, 512, r21);
  sa_mfma_kernel<4096, 512, 32, 2, 0, 64, 64, 128><<<8192, 256, 0, stream>>>(
      xyz, nx1, gidx1, (const float*)nullptr, s1w0, s1b0,
      nullptr, nullptr, g11h, g11l, s1b1, g12h, g12l, s1b2, f1);
  fps_kernel<512, 128, 64><<<32, 64, 0, stream>>>(nx1, nx2);
  bq_kernel<512, 64><<<1024, 256, 0, stream>>>(nx1, nx2, gidx2, 128, r22);
  sa_mfma_kernel<512, 128, 64, 1, 128, 128, 128, 256><<<4096, 256, 0, stream>>>(
      nx1, nx2, gidx2, f1, s2w0, s2b0,
      g20h, g20l, g21h, g21l, s2b1, g22h, g22l, s2b2, f2);
  sa3_kernel<259, 256, true, false><<<dim3(32, 4), 256, 0, stream>>>(nx2, f2, s3w0, s3b0, h1);
  sa3_kernel<256, 512, false, false><<<dim3(32, 8), 256, 0, stream>>>(h1, nullptr, s3w1, s3b1, h2);
  sa3_kernel<512, 1024, false, true><<<dim3(32, 16), 256, 0, stream>>>(h2, nullptr, s3w2, s3b2, feat);
  heads_kernel<<<32, 256, 0, stream>>>(feat, clsw, clsb, regw, regb, (float*)d_out);
}